// Round 1
// baseline (2535.867 us; speedup 1.0000x reference)
//
#include <hip/hip_runtime.h>

#define NN 50000        // nodes
#define NE 800000       // edges (without self loops)
#define ET 850000       // edges + self loops
#define GD 128          // input feature dim
#define D1 128          // HEADS*H1
#define NH 4            // heads layer 1
#define D2 64           // layer-2 dim
#define ENC_NEG_INF 0x007FFFFFu

__device__ __forceinline__ unsigned enc_f32(float f) {
    unsigned b = __float_as_uint(f);
    return (b & 0x80000000u) ? ~b : (b | 0x80000000u);
}
__device__ __forceinline__ float dec_f32(unsigned u) {
    unsigned b = (u & 0x80000000u) ? (u & 0x7FFFFFFFu) : ~u;
    return __uint_as_float(b);
}
__device__ __forceinline__ float lrelu(float x, float s) { return x > 0.f ? x : s * x; }

__device__ __forceinline__ void edge_sd(int e, const int* __restrict__ ei, int& s, int& d) {
    if (e < NE) { s = ei[e]; d = ei[NE + e]; }
    else { s = e - NE; d = s; }
}

// ---------------- init ----------------
__global__ void k_init(unsigned* m1, float* s1, unsigned* m2, float* s2, float* st) {
    int i = blockIdx.x * blockDim.x + threadIdx.x;
    if (i < NN * NH) { m1[i] = ENC_NEG_INF; s1[i] = 0.f; }
    if (i < NN)      { m2[i] = ENC_NEG_INF; s2[i] = 0.f; }
    if (i < 768)     st[i] = 0.f;
}

// ---------------- GEMM1: xw1 = x @ W1, plus per-head attention dots ----------------
__global__ void k_gemm1(const float* __restrict__ x, const float* __restrict__ W,
                        const float* __restrict__ as, const float* __restrict__ ad,
                        float* __restrict__ xw, float* __restrict__ al_s, float* __restrict__ al_d) {
    const int NR = 8;
    __shared__ float xs[NR][GD];
    int n0 = blockIdx.x * NR;
    int j = threadIdx.x;  // 0..127 (output column)
    for (int t = threadIdx.x; t < NR * GD; t += blockDim.x) {
        int r = t >> 7, k = t & 127;
        int n = n0 + r;
        xs[r][k] = (n < NN) ? x[n * GD + k] : 0.f;
    }
    __syncthreads();
    float acc[NR];
#pragma unroll
    for (int r = 0; r < NR; r++) acc[r] = 0.f;
    for (int k = 0; k < GD; k++) {
        float w = W[k * D1 + j];
#pragma unroll
        for (int r = 0; r < NR; r++) acc[r] += xs[r][k] * w;
    }
    int h = j >> 5, c = j & 31;
    float asj = as[j], adj = ad[j];  // a_src1/a_dst1 are [4][32] contiguous = index j
#pragma unroll
    for (int r = 0; r < NR; r++) {
        int n = n0 + r;
        if (n >= NN) break;  // uniform across block
        xw[n * D1 + j] = acc[r];
        float vs = acc[r] * asj, vd = acc[r] * adj;
#pragma unroll
        for (int m = 16; m >= 1; m >>= 1) { vs += __shfl_xor(vs, m); vd += __shfl_xor(vd, m); }
        if (c == 0) { al_s[n * NH + h] = vs; al_d[n * NH + h] = vd; }
    }
}

// ---------------- layer-1 edge kernels ----------------
__global__ void k_max1(const int* __restrict__ ei, const float* __restrict__ als,
                       const float* __restrict__ ald, unsigned* __restrict__ m1) {
    int idx = blockIdx.x * blockDim.x + threadIdx.x;
    if (idx >= ET * NH) return;
    int e = idx >> 2, h = idx & 3;
    int s, d; edge_sd(e, ei, s, d);
    float l = lrelu(als[s * NH + h] + ald[d * NH + h], 0.2f);
    atomicMax(&m1[d * NH + h], enc_f32(l));
}

__global__ void k_sum1(const int* __restrict__ ei, const float* __restrict__ als,
                       const float* __restrict__ ald, const unsigned* __restrict__ m1,
                       float* __restrict__ s1) {
    int idx = blockIdx.x * blockDim.x + threadIdx.x;
    if (idx >= ET * NH) return;
    int e = idx >> 2, h = idx & 3;
    int s, d; edge_sd(e, ei, s, d);
    float l = lrelu(als[s * NH + h] + ald[d * NH + h], 0.2f);
    float ex = __expf(l - dec_f32(m1[d * NH + h]));
    atomicAdd(&s1[d * NH + h], ex);
}

__global__ void k_scatter1(const int* __restrict__ ei, const float* __restrict__ als,
                           const float* __restrict__ ald, const unsigned* __restrict__ m1,
                           const float* __restrict__ s1, const float* __restrict__ xw,
                           float* __restrict__ agg) {
    long long idx = (long long)blockIdx.x * blockDim.x + threadIdx.x;
    if (idx >= (long long)ET * 32) return;
    int e = (int)(idx >> 5), q = (int)(idx & 31);
    int h = q >> 3, f0 = q << 2;
    int s, d; edge_sd(e, ei, s, d);
    float l = lrelu(als[s * NH + h] + ald[d * NH + h], 0.2f);
    float alpha = __expf(l - dec_f32(m1[d * NH + h])) / (s1[d * NH + h] + 1e-16f);
    const float4 v = *(const float4*)(xw + s * D1 + f0);
    float* o = agg + d * D1 + f0;
    atomicAdd(o + 0, alpha * v.x);
    atomicAdd(o + 1, alpha * v.y);
    atomicAdd(o + 2, alpha * v.z);
    atomicAdd(o + 3, alpha * v.w);
}

// ---------------- batchnorm ----------------
template <int D>
__global__ void k_bnstats(const float* __restrict__ x, float* __restrict__ sum, float* __restrict__ sq) {
    int j = threadIdx.x;
    float s = 0.f, q = 0.f;
    for (int r = blockIdx.x; r < NN; r += gridDim.x) {
        float v = x[r * D + j];
        s += v; q += v * v;
    }
    atomicAdd(&sum[j], s);
    atomicAdd(&sq[j], q);
}

template <int D>
__global__ void k_bnfinal(const float* __restrict__ sum, const float* __restrict__ sq,
                          float* __restrict__ mean, float* __restrict__ rstd) {
    int j = threadIdx.x;
    float mu = sum[j] / (float)NN;
    float var = sq[j] / (float)NN - mu * mu;
    mean[j] = mu;
    rstd[j] = rsqrtf(var + 1e-5f);
}

template <int D>
__global__ void k_bnapply(const float* __restrict__ x, const float* __restrict__ mean,
                          const float* __restrict__ rstd, const float* __restrict__ g,
                          const float* __restrict__ b, float* __restrict__ y) {
    int idx = blockIdx.x * blockDim.x + threadIdx.x;
    if (idx >= NN * D) return;
    int c = idx & (D - 1);
    float v = (x[idx] - mean[c]) * rstd[c] * g[c] + b[c];
    y[idx] = lrelu(v, 0.01f);
}

// ---------------- GEMM2: xw2 = x2 @ W2 (+ single-head attention dots) ----------------
__global__ void k_gemm2(const float* __restrict__ x, const float* __restrict__ W,
                        const float* __restrict__ as, const float* __restrict__ ad,
                        float* __restrict__ xw, float* __restrict__ al_s, float* __restrict__ al_d) {
    const int NR = 8;
    __shared__ float xs[NR][D1];
    int n0 = blockIdx.x * NR;
    int j = threadIdx.x;  // 0..63
    for (int t = threadIdx.x; t < NR * D1; t += blockDim.x) {
        int r = t >> 7, k = t & 127;
        int n = n0 + r;
        xs[r][k] = (n < NN) ? x[n * D1 + k] : 0.f;
    }
    __syncthreads();
    float acc[NR];
#pragma unroll
    for (int r = 0; r < NR; r++) acc[r] = 0.f;
    for (int k = 0; k < D1; k++) {
        float w = W[k * D2 + j];
#pragma unroll
        for (int r = 0; r < NR; r++) acc[r] += xs[r][k] * w;
    }
    float asj = as[j], adj = ad[j];
#pragma unroll
    for (int r = 0; r < NR; r++) {
        int n = n0 + r;
        if (n >= NN) break;
        xw[n * D2 + j] = acc[r];
        float vs = acc[r] * asj, vd = acc[r] * adj;
#pragma unroll
        for (int m = 32; m >= 1; m >>= 1) { vs += __shfl_xor(vs, m); vd += __shfl_xor(vd, m); }
        if (j == 0) { al_s[n] = vs; al_d[n] = vd; }
    }
}

// ---------------- layer-2 edge kernels ----------------
__global__ void k_max2(const int* __restrict__ ei, const float* __restrict__ als,
                       const float* __restrict__ ald, unsigned* __restrict__ m2) {
    int e = blockIdx.x * blockDim.x + threadIdx.x;
    if (e >= ET) return;
    int s, d; edge_sd(e, ei, s, d);
    float l = lrelu(als[s] + ald[d], 0.2f);
    atomicMax(&m2[d], enc_f32(l));
}

__global__ void k_sum2(const int* __restrict__ ei, const float* __restrict__ als,
                       const float* __restrict__ ald, const unsigned* __restrict__ m2,
                       float* __restrict__ s2) {
    int e = blockIdx.x * blockDim.x + threadIdx.x;
    if (e >= ET) return;
    int s, d; edge_sd(e, ei, s, d);
    float l = lrelu(als[s] + ald[d], 0.2f);
    atomicAdd(&s2[d], __expf(l - dec_f32(m2[d])));
}

__global__ void k_scatter2(const int* __restrict__ ei, const float* __restrict__ als,
                           const float* __restrict__ ald, const unsigned* __restrict__ m2,
                           const float* __restrict__ s2, const float* __restrict__ xw,
                           float* __restrict__ out) {
    long long idx = (long long)blockIdx.x * blockDim.x + threadIdx.x;
    if (idx >= (long long)ET * 16) return;
    int e = (int)(idx >> 4), q = (int)(idx & 15);
    int f0 = q << 2;
    int s, d; edge_sd(e, ei, s, d);
    float l = lrelu(als[s] + ald[d], 0.2f);
    float alpha = __expf(l - dec_f32(m2[d])) / (s2[d] + 1e-16f);
    const float4 v = *(const float4*)(xw + s * D2 + f0);
    float* o = out + d * D2 + f0;
    atomicAdd(o + 0, alpha * v.x);
    atomicAdd(o + 1, alpha * v.y);
    atomicAdd(o + 2, alpha * v.z);
    atomicAdd(o + 3, alpha * v.w);
}

extern "C" void kernel_launch(void* const* d_in, const int* in_sizes, int n_in,
                              void* d_out, int out_size, void* d_ws, size_t ws_size,
                              hipStream_t stream) {
    const float* x   = (const float*)d_in[0];
    const int*   ei  = (const int*)d_in[2];
    const float* W1  = (const float*)d_in[3];
    const float* as1 = (const float*)d_in[4];
    const float* ad1 = (const float*)d_in[5];
    const float* g1  = (const float*)d_in[7];
    const float* be1 = (const float*)d_in[8];
    const float* W2  = (const float*)d_in[9];
    const float* as2 = (const float*)d_in[10];
    const float* ad2 = (const float*)d_in[11];
    const float* g2  = (const float*)d_in[13];
    const float* be2 = (const float*)d_in[14];
    float* out = (float*)d_out;

    float* ws = (float*)d_ws;
    float*    xw1   = ws;                         // 6.4M floats (reused as xw2 later)
    float*    al_s1 = xw1 + 6400000;              // 200k
    float*    al_d1 = al_s1 + 200000;             // 200k
    unsigned* m1    = (unsigned*)(al_d1 + 200000);// 200k
    float*    s1    = (float*)(m1 + 200000);      // 200k
    float*    agg1  = s1 + 200000;                // 6.4M (BN applied in place -> x2)
    float*    al_s2 = agg1 + 6400000;             // 50k
    float*    al_d2 = al_s2 + 50000;              // 50k
    unsigned* m2    = (unsigned*)(al_d2 + 50000); // 50k
    float*    s2    = (float*)(m2 + 50000);       // 50k
    float*    st    = s2 + 50000;                 // 768 floats of stats
    float*    xw2   = ws;                         // overlaps xw1 (dead by then), 3.2M

    // fresh state every launch (graph-replay safe)
    hipMemsetAsync(agg1, 0, (size_t)NN * D1 * sizeof(float), stream);
    hipMemsetAsync(out, 0, (size_t)NN * D2 * sizeof(float), stream);
    k_init<<<(NN * NH + 255) / 256, 256, 0, stream>>>(m1, s1, m2, s2, st);

    // ---- layer 1 ----
    k_gemm1<<<(NN + 7) / 8, 128, 0, stream>>>(x, W1, as1, ad1, xw1, al_s1, al_d1);
    k_max1<<<(ET * NH + 255) / 256, 256, 0, stream>>>(ei, al_s1, al_d1, m1);
    k_sum1<<<(ET * NH + 255) / 256, 256, 0, stream>>>(ei, al_s1, al_d1, m1, s1);
    {
        long long tot = (long long)ET * 32;
        k_scatter1<<<(unsigned)((tot + 255) / 256), 256, 0, stream>>>(ei, al_s1, al_d1, m1, s1, xw1, agg1);
    }
    k_bnstats<D1><<<256, D1, 0, stream>>>(agg1, st, st + 128);
    k_bnfinal<D1><<<1, D1, 0, stream>>>(st, st + 128, st + 256, st + 384);
    k_bnapply<D1><<<(NN * D1 + 255) / 256, 256, 0, stream>>>(agg1, st + 256, st + 384, g1, be1, agg1);

    // ---- layer 2 ----
    k_gemm2<<<(NN + 7) / 8, 64, 0, stream>>>(agg1, W2, as2, ad2, xw2, al_s2, al_d2);
    k_max2<<<(ET + 255) / 256, 256, 0, stream>>>(ei, al_s2, al_d2, m2);
    k_sum2<<<(ET + 255) / 256, 256, 0, stream>>>(ei, al_s2, al_d2, m2, s2);
    {
        long long tot = (long long)ET * 16;
        k_scatter2<<<(unsigned)((tot + 255) / 256), 256, 0, stream>>>(ei, al_s2, al_d2, m2, s2, xw2, out);
    }
    k_bnstats<D2><<<256, D2, 0, stream>>>(out, st + 512, st + 576);
    k_bnfinal<D2><<<1, D2, 0, stream>>>(st + 512, st + 576, st + 640, st + 704);
    k_bnapply<D2><<<(NN * D2 + 255) / 256, 256, 0, stream>>>(out, st + 640, st + 704, g2, be2, out);
}

// Round 3
// 446.921 us; speedup vs baseline: 5.6741x; 5.6741x over previous
//
#include <hip/hip_runtime.h>

#define NN 50000        // nodes
#define NE 800000       // edges (without self loops)
#define ET 850000       // edges + self loops
#define GD 128          // input feature dim
#define D1 128          // HEADS*H1
#define NH 4            // heads layer 1
#define D2 64           // layer-2 dim
#define NB_SCAN 196     // ceil(NN/256)

typedef unsigned short u16;

__device__ __forceinline__ float lrelu(float x, float s) { return x > 0.f ? x : s * x; }

__device__ __forceinline__ void edge_sd(int e, const int* __restrict__ ei, int& s, int& d) {
    if (e < NE) { s = ei[e]; d = ei[NE + e]; }
    else { s = e - NE; d = s; }
}

// ---------------- CSR build ----------------
__global__ void k_hist(const int* __restrict__ ei, int* __restrict__ cnt) {
    int e = blockIdx.x * blockDim.x + threadIdx.x;
    if (e >= ET) return;
    int s, d; edge_sd(e, ei, s, d);
    atomicAdd(&cnt[d], 1);
}

__global__ void k_blocksum(const int* __restrict__ cnt, int* __restrict__ part) {
    __shared__ int r[256];
    int t = threadIdx.x, i = blockIdx.x * 256 + t;
    r[t] = (i < NN) ? cnt[i] : 0;
    __syncthreads();
    for (int s = 128; s >= 1; s >>= 1) {
        if (t < s) r[t] += r[t + s];
        __syncthreads();
    }
    if (t == 0) part[blockIdx.x] = r[0];
}

__global__ void k_scanpart(int* __restrict__ part) {  // exclusive, one block of 256
    __shared__ int r[256];
    int t = threadIdx.x;
    r[t] = (t < NB_SCAN) ? part[t] : 0;
    __syncthreads();
    for (int off = 1; off < 256; off <<= 1) {
        int v = (t >= off) ? r[t - off] : 0;
        __syncthreads();
        r[t] += v;
        __syncthreads();
    }
    if (t < NB_SCAN) part[t] = t ? r[t - 1] : 0;
}

__global__ void k_scanfinal(const int* __restrict__ cnt, const int* __restrict__ part,
                            int* __restrict__ row_ptr) {
    __shared__ int r[256];
    int b = blockIdx.x, t = threadIdx.x, i = b * 256 + t;
    int v = (i < NN) ? cnt[i] : 0;
    r[t] = v;
    __syncthreads();
    for (int off = 1; off < 256; off <<= 1) {
        int u = (t >= off) ? r[t - off] : 0;
        __syncthreads();
        r[t] += u;
        __syncthreads();
    }
    if (i < NN) row_ptr[i] = part[b] + (t ? r[t - 1] : 0);
    if (i == NN - 1) row_ptr[NN] = part[b] + r[t];
}

__global__ void k_copycur(const int* __restrict__ row_ptr, int* __restrict__ cur) {
    int i = blockIdx.x * blockDim.x + threadIdx.x;
    if (i < NN) cur[i] = row_ptr[i];
}

__global__ void k_fill(const int* __restrict__ ei, int* __restrict__ cur, u16* __restrict__ csr_src) {
    int e = blockIdx.x * blockDim.x + threadIdx.x;
    if (e >= ET) return;
    int s, d; edge_sd(e, ei, s, d);
    int pos = atomicAdd(&cur[d], 1);
    csr_src[pos] = (u16)s;
}

// ---------------- GEMM1: xw1 = x @ W1, plus per-head attention dots ----------------
__global__ void k_gemm1(const float* __restrict__ x, const float* __restrict__ W,
                        const float* __restrict__ as, const float* __restrict__ ad,
                        float* __restrict__ xw, float* __restrict__ al_s, float* __restrict__ al_d) {
    const int NR = 8;
    __shared__ float xs[NR][GD];
    int n0 = blockIdx.x * NR;
    int j = threadIdx.x;  // 0..127
    for (int t = threadIdx.x; t < NR * GD; t += blockDim.x) {
        int r = t >> 7, k = t & 127;
        int n = n0 + r;
        xs[r][k] = (n < NN) ? x[n * GD + k] : 0.f;
    }
    __syncthreads();
    float acc[NR];
#pragma unroll
    for (int r = 0; r < NR; r++) acc[r] = 0.f;
    for (int k = 0; k < GD; k++) {
        float w = W[k * D1 + j];
#pragma unroll
        for (int r = 0; r < NR; r++) acc[r] += xs[r][k] * w;
    }
    int h = j >> 5, c = j & 31;
    float asj = as[j], adj = ad[j];
#pragma unroll
    for (int r = 0; r < NR; r++) {
        int n = n0 + r;
        if (n >= NN) break;
        xw[n * D1 + j] = acc[r];
        float vs = acc[r] * asj, vd = acc[r] * adj;
#pragma unroll
        for (int m = 16; m >= 1; m >>= 1) { vs += __shfl_xor(vs, m); vd += __shfl_xor(vd, m); }
        if (c == 0) { al_s[n * NH + h] = vs; al_d[n * NH + h] = vd; }
    }
}

// ---------------- fused GAT layer 1 (per-destination block, no atomics) ----------------
__global__ void k_gat1(const int* __restrict__ row_ptr, const u16* __restrict__ csr_src,
                       const float* __restrict__ als, const float* __restrict__ ald,
                       const float* __restrict__ xw, float* __restrict__ out) {
    const int d = blockIdx.x;
    const int beg = row_ptr[d];
    const int deg = row_ptr[d + 1] - beg;
    const int tid = threadIdx.x;  // 128

    __shared__ int   s_src[128];
    __shared__ float s_al[128 * NH];
    __shared__ float s_red[128 * NH];

    const float4 adv = *(const float4*)(ald + d * NH);

    // pass 1: per-head max
    float mx[NH] = {-1e30f, -1e30f, -1e30f, -1e30f};
    for (int i = tid; i < deg; i += 128) {
        int s = csr_src[beg + i];
        const float4 a = *(const float4*)(als + s * NH);
        mx[0] = fmaxf(mx[0], lrelu(a.x + adv.x, 0.2f));
        mx[1] = fmaxf(mx[1], lrelu(a.y + adv.y, 0.2f));
        mx[2] = fmaxf(mx[2], lrelu(a.z + adv.z, 0.2f));
        mx[3] = fmaxf(mx[3], lrelu(a.w + adv.w, 0.2f));
    }
#pragma unroll
    for (int h = 0; h < NH; h++) s_red[tid * NH + h] = mx[h];
    __syncthreads();
    for (int st = 64; st >= 1; st >>= 1) {
        if (tid < st) {
#pragma unroll
            for (int h = 0; h < NH; h++)
                s_red[tid * NH + h] = fmaxf(s_red[tid * NH + h], s_red[(tid + st) * NH + h]);
        }
        __syncthreads();
    }
    const float m0 = s_red[0], m1 = s_red[1], m2 = s_red[2], m3 = s_red[3];
    __syncthreads();

    // pass 2: per-head sum of exp
    float sm[NH] = {0.f, 0.f, 0.f, 0.f};
    for (int i = tid; i < deg; i += 128) {
        int s = csr_src[beg + i];
        const float4 a = *(const float4*)(als + s * NH);
        sm[0] += __expf(lrelu(a.x + adv.x, 0.2f) - m0);
        sm[1] += __expf(lrelu(a.y + adv.y, 0.2f) - m1);
        sm[2] += __expf(lrelu(a.z + adv.z, 0.2f) - m2);
        sm[3] += __expf(lrelu(a.w + adv.w, 0.2f) - m3);
    }
#pragma unroll
    for (int h = 0; h < NH; h++) s_red[tid * NH + h] = sm[h];
    __syncthreads();
    for (int st = 64; st >= 1; st >>= 1) {
        if (tid < st) {
#pragma unroll
            for (int h = 0; h < NH; h++)
                s_red[tid * NH + h] += s_red[(tid + st) * NH + h];
        }
        __syncthreads();
    }
    const float z0 = s_red[0] + 1e-16f, z1 = s_red[1] + 1e-16f;
    const float z2 = s_red[2] + 1e-16f, z3 = s_red[3] + 1e-16f;
    __syncthreads();

    // pass 3: accumulate alpha * xw[src]
    const int h = tid >> 5;
    float acc = 0.f;
    for (int base = 0; base < deg; base += 128) {
        int cnt = min(128, deg - base);
        for (int i = tid; i < cnt; i += 128) {
            int s = csr_src[beg + base + i];
            s_src[i] = s;
            const float4 a = *(const float4*)(als + s * NH);
            s_al[i * NH + 0] = __expf(lrelu(a.x + adv.x, 0.2f) - m0) / z0;
            s_al[i * NH + 1] = __expf(lrelu(a.y + adv.y, 0.2f) - m1) / z1;
            s_al[i * NH + 2] = __expf(lrelu(a.z + adv.z, 0.2f) - m2) / z2;
            s_al[i * NH + 3] = __expf(lrelu(a.w + adv.w, 0.2f) - m3) / z3;
        }
        __syncthreads();
        for (int i = 0; i < cnt; i++)
            acc += s_al[i * NH + h] * xw[s_src[i] * D1 + tid];
        __syncthreads();
    }
    out[d * D1 + tid] = acc;
}

// ---------------- batchnorm ----------------
template <int D>
__global__ void k_bnstats(const float* __restrict__ x, float* __restrict__ sum, float* __restrict__ sq) {
    int j = threadIdx.x;
    float s = 0.f, q = 0.f;
    for (int r = blockIdx.x; r < NN; r += gridDim.x) {
        float v = x[r * D + j];
        s += v; q += v * v;
    }
    atomicAdd(&sum[j], s);
    atomicAdd(&sq[j], q);
}

template <int D>
__global__ void k_bnfinal(const float* __restrict__ sum, const float* __restrict__ sq,
                          float* __restrict__ mean, float* __restrict__ rstd) {
    int j = threadIdx.x;
    float mu = sum[j] / (float)NN;
    float var = sq[j] / (float)NN - mu * mu;
    mean[j] = mu;
    rstd[j] = rsqrtf(var + 1e-5f);
}

template <int D>
__global__ void k_bnapply(const float* __restrict__ x, const float* __restrict__ mean,
                          const float* __restrict__ rstd, const float* __restrict__ g,
                          const float* __restrict__ b, float* __restrict__ y) {
    int idx = blockIdx.x * blockDim.x + threadIdx.x;
    if (idx >= NN * D) return;
    int c = idx & (D - 1);
    float v = (x[idx] - mean[c]) * rstd[c] * g[c] + b[c];
    y[idx] = lrelu(v, 0.01f);
}

// ---------------- GEMM2 ----------------
__global__ void k_gemm2(const float* __restrict__ x, const float* __restrict__ W,
                        const float* __restrict__ as, const float* __restrict__ ad,
                        float* __restrict__ xw, float* __restrict__ al_s, float* __restrict__ al_d) {
    const int NR = 8;
    __shared__ float xs[NR][D1];
    int n0 = blockIdx.x * NR;
    int j = threadIdx.x;  // 0..63
    for (int t = threadIdx.x; t < NR * D1; t += blockDim.x) {
        int r = t >> 7, k = t & 127;
        int n = n0 + r;
        xs[r][k] = (n < NN) ? x[n * D1 + k] : 0.f;
    }
    __syncthreads();
    float acc[NR];
#pragma unroll
    for (int r = 0; r < NR; r++) acc[r] = 0.f;
    for (int k = 0; k < D1; k++) {
        float w = W[k * D2 + j];
#pragma unroll
        for (int r = 0; r < NR; r++) acc[r] += xs[r][k] * w;
    }
    float asj = as[j], adj = ad[j];
#pragma unroll
    for (int r = 0; r < NR; r++) {
        int n = n0 + r;
        if (n >= NN) break;
        xw[n * D2 + j] = acc[r];
        float vs = acc[r] * asj, vd = acc[r] * adj;
#pragma unroll
        for (int m = 32; m >= 1; m >>= 1) { vs += __shfl_xor(vs, m); vd += __shfl_xor(vd, m); }
        if (j == 0) { al_s[n] = vs; al_d[n] = vd; }
    }
}

// ---------------- fused GAT layer 2 (single head, one wave per node) ----------------
__global__ void k_gat2(const int* __restrict__ row_ptr, const u16* __restrict__ csr_src,
                       const float* __restrict__ als, const float* __restrict__ ald,
                       const float* __restrict__ xw, float* __restrict__ out) {
    const int d = blockIdx.x;
    const int beg = row_ptr[d];
    const int deg = row_ptr[d + 1] - beg;
    const int tid = threadIdx.x;  // 64

    __shared__ int   s_src[64];
    __shared__ float s_al[64];

    const float add = ald[d];

    float mx = -1e30f;
    for (int i = tid; i < deg; i += 64) {
        int s = csr_src[beg + i];
        mx = fmaxf(mx, lrelu(als[s] + add, 0.2f));
    }
#pragma unroll
    for (int m = 32; m >= 1; m >>= 1) mx = fmaxf(mx, __shfl_xor(mx, m));

    float sm = 0.f;
    for (int i = tid; i < deg; i += 64) {
        int s = csr_src[beg + i];
        sm += __expf(lrelu(als[s] + add, 0.2f) - mx);
    }
#pragma unroll
    for (int m = 32; m >= 1; m >>= 1) sm += __shfl_xor(sm, m);
    const float z = sm + 1e-16f;

    float acc = 0.f;
    for (int base = 0; base < deg; base += 64) {
        int cnt = min(64, deg - base);
        if (tid < cnt) {
            int s = csr_src[beg + base + tid];
            s_src[tid] = s;
            s_al[tid] = __expf(lrelu(als[s] + add, 0.2f) - mx) / z;
        }
        __syncthreads();
        for (int i = 0; i < cnt; i++)
            acc += s_al[i] * xw[s_src[i] * D2 + tid];
        __syncthreads();
    }
    out[d * D2 + tid] = acc;
}

extern "C" void kernel_launch(void* const* d_in, const int* in_sizes, int n_in,
                              void* d_out, int out_size, void* d_ws, size_t ws_size,
                              hipStream_t stream) {
    const float* x   = (const float*)d_in[0];
    const int*   ei  = (const int*)d_in[2];
    const float* W1  = (const float*)d_in[3];
    const float* as1 = (const float*)d_in[4];
    const float* ad1 = (const float*)d_in[5];
    const float* g1  = (const float*)d_in[7];
    const float* be1 = (const float*)d_in[8];
    const float* W2  = (const float*)d_in[9];
    const float* as2 = (const float*)d_in[10];
    const float* ad2 = (const float*)d_in[11];
    const float* g2  = (const float*)d_in[13];
    const float* be2 = (const float*)d_in[14];
    float* out = (float*)d_out;

    float* ws = (float*)d_ws;
    // Packed layout, total 54,903,860 B < 55.2 MB (proven capacity from R1).
    float* xw1   = ws;                   // [0, 6.4M) floats; layer-1 only
    float* xw2   = ws;                   // [0, 3.2M)  reuses dead xw1 region
    float* al_s2 = ws + 3200000;         // 50k  (inside dead xw1 region)
    float* al_d2 = ws + 3250000;         // 50k  (inside dead xw1 region)
    float* al_s1 = ws + 6400000;         // 200k
    float* al_d1 = al_s1 + 200000;       // 200k
    float* agg1  = al_d1 + 200000;       // 6.4M (BN in place -> x2)
    int*   row_ptr = (int*)(agg1 + 6400000);  // 50,001 ints
    int*   cur     = row_ptr + 50001;         // 50,000 ints (standalone)
    int*   part    = cur + 50000;             // 196 ints
    float* st      = (float*)(part + 196);    // 768 floats (standalone)
    u16*   csr_src = (u16*)(st + 768);        // 850,000 u16

    // fresh state every launch (graph-replay safe)
    hipMemsetAsync(cur, 0, (size_t)NN * sizeof(int), stream);
    hipMemsetAsync(st, 0, 768 * sizeof(float), stream);

    // ---- CSR build (counts in `cur`) ----
    k_hist<<<(ET + 255) / 256, 256, 0, stream>>>(ei, cur);
    k_blocksum<<<NB_SCAN, 256, 0, stream>>>(cur, part);
    k_scanpart<<<1, 256, 0, stream>>>(part);
    k_scanfinal<<<NB_SCAN, 256, 0, stream>>>(cur, part, row_ptr);
    k_copycur<<<NB_SCAN, 256, 0, stream>>>(row_ptr, cur);
    k_fill<<<(ET + 255) / 256, 256, 0, stream>>>(ei, cur, csr_src);

    // ---- layer 1 ----
    k_gemm1<<<(NN + 7) / 8, 128, 0, stream>>>(x, W1, as1, ad1, xw1, al_s1, al_d1);
    k_gat1<<<NN, 128, 0, stream>>>(row_ptr, csr_src, al_s1, al_d1, xw1, agg1);
    k_bnstats<D1><<<256, D1, 0, stream>>>(agg1, st, st + 128);
    k_bnfinal<D1><<<1, D1, 0, stream>>>(st, st + 128, st + 256, st + 384);
    k_bnapply<D1><<<(NN * D1 + 255) / 256, 256, 0, stream>>>(agg1, st + 256, st + 384, g1, be1, agg1);

    // ---- layer 2 ----
    k_gemm2<<<(NN + 7) / 8, 64, 0, stream>>>(agg1, W2, as2, ad2, xw2, al_s2, al_d2);
    k_gat2<<<NN, 64, 0, stream>>>(row_ptr, csr_src, al_s2, al_d2, xw2, out);
    k_bnstats<D2><<<256, D2, 0, stream>>>(out, st + 512, st + 576);
    k_bnfinal<D2><<<1, D2, 0, stream>>>(st + 512, st + 576, st + 640, st + 704);
    k_bnapply<D2><<<(NN * D2 + 255) / 256, 256, 0, stream>>>(out, st + 640, st + 704, g2, be2, out);
}

// Round 4
// 385.213 us; speedup vs baseline: 6.5830x; 1.1602x over previous
//
#include <hip/hip_runtime.h>

#define NN 50000        // nodes
#define NE 800000       // edges (without self loops)
#define ET 850000       // edges + self loops
#define GD 128          // input feature dim
#define D1 128          // HEADS*H1
#define NH 4            // heads layer 1
#define D2 64           // layer-2 dim
#define NB_SCAN 196     // ceil(NN/256)

typedef unsigned short u16;

__device__ __forceinline__ float lrelu(float x, float s) { return x > 0.f ? x : s * x; }

__device__ __forceinline__ void edge_sd(int e, const int* __restrict__ ei, int& s, int& d) {
    if (e < NE) { s = ei[e]; d = ei[NE + e]; }
    else { s = e - NE; d = s; }
}

// ---------------- CSR build ----------------
__global__ void k_hist(const int* __restrict__ ei, int* __restrict__ cnt) {
    int e = blockIdx.x * blockDim.x + threadIdx.x;
    if (e >= ET) return;
    int s, d; edge_sd(e, ei, s, d);
    atomicAdd(&cnt[d], 1);
}

__global__ void k_blocksum(const int* __restrict__ cnt, int* __restrict__ part) {
    __shared__ int r[256];
    int t = threadIdx.x, i = blockIdx.x * 256 + t;
    r[t] = (i < NN) ? cnt[i] : 0;
    __syncthreads();
    for (int s = 128; s >= 1; s >>= 1) {
        if (t < s) r[t] += r[t + s];
        __syncthreads();
    }
    if (t == 0) part[blockIdx.x] = r[0];
}

__global__ void k_scanpart(int* __restrict__ part) {  // exclusive, one block of 256
    __shared__ int r[256];
    int t = threadIdx.x;
    r[t] = (t < NB_SCAN) ? part[t] : 0;
    __syncthreads();
    for (int off = 1; off < 256; off <<= 1) {
        int v = (t >= off) ? r[t - off] : 0;
        __syncthreads();
        r[t] += v;
        __syncthreads();
    }
    if (t < NB_SCAN) part[t] = t ? r[t - 1] : 0;
}

__global__ void k_scanfinal(const int* __restrict__ cnt, const int* __restrict__ part,
                            int* __restrict__ row_ptr, int* __restrict__ cur) {
    __shared__ int r[256];
    int b = blockIdx.x, t = threadIdx.x, i = b * 256 + t;
    int v = (i < NN) ? cnt[i] : 0;
    r[t] = v;
    __syncthreads();
    for (int off = 1; off < 256; off <<= 1) {
        int u = (t >= off) ? r[t - off] : 0;
        __syncthreads();
        r[t] += u;
        __syncthreads();
    }
    if (i < NN) {
        int rp = part[b] + (t ? r[t - 1] : 0);
        row_ptr[i] = rp;
        cur[i] = rp;
    }
    if (i == NN - 1) row_ptr[NN] = part[b] + r[t];
}

__global__ void k_fill(const int* __restrict__ ei, int* __restrict__ cur, u16* __restrict__ csr_src) {
    int e = blockIdx.x * blockDim.x + threadIdx.x;
    if (e >= ET) return;
    int s, d; edge_sd(e, ei, s, d);
    int pos = atomicAdd(&cur[d], 1);
    csr_src[pos] = (u16)s;
}

// ---------------- GEMM1: xw1 = x @ W1, plus per-head attention dots ----------------
__global__ void k_gemm1(const float* __restrict__ x, const float* __restrict__ W,
                        const float* __restrict__ as, const float* __restrict__ ad,
                        float* __restrict__ xw, float* __restrict__ al_s, float* __restrict__ al_d) {
    const int NR = 8;
    __shared__ float xs[NR][GD];
    int n0 = blockIdx.x * NR;
    int j = threadIdx.x;  // 0..127
    for (int t = threadIdx.x; t < NR * GD; t += blockDim.x) {
        int r = t >> 7, k = t & 127;
        int n = n0 + r;
        xs[r][k] = (n < NN) ? x[n * GD + k] : 0.f;
    }
    __syncthreads();
    float acc[NR];
#pragma unroll
    for (int r = 0; r < NR; r++) acc[r] = 0.f;
    for (int k = 0; k < GD; k++) {
        float w = W[k * D1 + j];
#pragma unroll
        for (int r = 0; r < NR; r++) acc[r] += xs[r][k] * w;
    }
    int h = j >> 5, c = j & 31;
    float asj = as[j], adj = ad[j];
#pragma unroll
    for (int r = 0; r < NR; r++) {
        int n = n0 + r;
        if (n >= NN) break;
        xw[n * D1 + j] = acc[r];
        float vs = acc[r] * asj, vd = acc[r] * adj;
#pragma unroll
        for (int m = 16; m >= 1; m >>= 1) { vs += __shfl_xor(vs, m); vd += __shfl_xor(vd, m); }
        if (c == 0) { al_s[n * NH + h] = vs; al_d[n * NH + h] = vd; }
    }
}

// ---------------- fused GAT layer 1: one wave per destination ----------------
__global__ void k_gat1(const int* __restrict__ row_ptr, const u16* __restrict__ csr_src,
                       const float* __restrict__ als, const float* __restrict__ ald,
                       const float* __restrict__ xw, float* __restrict__ out) {
    const int d = blockIdx.x;
    const int beg = row_ptr[d];
    const int deg = row_ptr[d + 1] - beg;
    const int lane = threadIdx.x;  // 64

    __shared__ int   s_src[64];
    __shared__ float s_al[64 * NH];

    const float4 adv = *(const float4*)(ald + d * NH);

    // pass A: per-head sum of exp (no max-shift: logits are O(1), exp is safe;
    // softmax is shift-invariant so result matches the reference exactly in math)
    float sx = 0.f, sy = 0.f, sz = 0.f, sw = 0.f;
    for (int i = lane; i < deg; i += 64) {
        int s = csr_src[beg + i];
        const float4 a = *(const float4*)(als + s * NH);
        sx += __expf(lrelu(a.x + adv.x, 0.2f));
        sy += __expf(lrelu(a.y + adv.y, 0.2f));
        sz += __expf(lrelu(a.z + adv.z, 0.2f));
        sw += __expf(lrelu(a.w + adv.w, 0.2f));
    }
#pragma unroll
    for (int m = 32; m >= 1; m >>= 1) {
        sx += __shfl_xor(sx, m); sy += __shfl_xor(sy, m);
        sz += __shfl_xor(sz, m); sw += __shfl_xor(sw, m);
    }
    const float z0 = 1.f / (sx + 1e-16f), z1 = 1.f / (sy + 1e-16f);
    const float z2 = 1.f / (sz + 1e-16f), z3 = 1.f / (sw + 1e-16f);

    // pass B: accumulate alpha * xw[src]; lane owns features 2*lane, 2*lane+1
    const int h = lane >> 4;  // head of feature 2*lane
    float ax = 0.f, ay = 0.f;
    for (int base = 0; base < deg; base += 64) {
        int cnt = min(64, deg - base);
        if (lane < cnt) {
            int s = csr_src[beg + base + lane];
            s_src[lane] = s;
            const float4 a = *(const float4*)(als + s * NH);
            s_al[lane * NH + 0] = __expf(lrelu(a.x + adv.x, 0.2f)) * z0;
            s_al[lane * NH + 1] = __expf(lrelu(a.y + adv.y, 0.2f)) * z1;
            s_al[lane * NH + 2] = __expf(lrelu(a.z + adv.z, 0.2f)) * z2;
            s_al[lane * NH + 3] = __expf(lrelu(a.w + adv.w, 0.2f)) * z3;
        }
        __syncthreads();
#pragma unroll 4
        for (int i = 0; i < cnt; i++) {
            float al = s_al[i * NH + h];
            const float2 v = *(const float2*)(xw + s_src[i] * D1 + 2 * lane);
            ax += al * v.x;
            ay += al * v.y;
        }
        __syncthreads();
    }
    *(float2*)(out + d * D1 + 2 * lane) = make_float2(ax, ay);
}

// ---------------- batchnorm ----------------
template <int D>
__global__ void k_bnstats(const float* __restrict__ x, float* __restrict__ sum, float* __restrict__ sq) {
    int j = threadIdx.x;
    float s = 0.f, q = 0.f;
    for (int r = blockIdx.x; r < NN; r += gridDim.x) {
        float v = x[r * D + j];
        s += v; q += v * v;
    }
    atomicAdd(&sum[j], s);
    atomicAdd(&sq[j], q);
}

// emits scale/shift so BN+affine is a single FMA downstream
__global__ void k_bnfinal(const float* __restrict__ sum, const float* __restrict__ sq,
                          const float* __restrict__ g, const float* __restrict__ b,
                          float* __restrict__ scale, float* __restrict__ shift) {
    int j = threadIdx.x;
    float mu = sum[j] / (float)NN;
    float var = sq[j] / (float)NN - mu * mu;
    float sc = rsqrtf(var + 1e-5f) * g[j];
    scale[j] = sc;
    shift[j] = b[j] - mu * sc;
}

// final BN+lrelu for layer-2 output (12.8 MB, float4)
__global__ void k_bnapply2(const float* __restrict__ x, const float* __restrict__ scale,
                           const float* __restrict__ shift, float* __restrict__ y) {
    int idx = blockIdx.x * blockDim.x + threadIdx.x;
    if (idx >= NN * D2 / 4) return;
    float4 v = ((const float4*)x)[idx];
    int c = (idx * 4) & (D2 - 1);
    v.x = lrelu(v.x * scale[c + 0] + shift[c + 0], 0.01f);
    v.y = lrelu(v.y * scale[c + 1] + shift[c + 1], 0.01f);
    v.z = lrelu(v.z * scale[c + 2] + shift[c + 2], 0.01f);
    v.w = lrelu(v.w * scale[c + 3] + shift[c + 3], 0.01f);
    ((float4*)y)[idx] = v;
}

// ---------------- GEMM2 with fused BN1-apply + lrelu on the fly ----------------
__global__ void k_gemm2(const float* __restrict__ x, const float* __restrict__ scale,
                        const float* __restrict__ shift, const float* __restrict__ W,
                        const float* __restrict__ as, const float* __restrict__ ad,
                        float* __restrict__ xw, float* __restrict__ al_s, float* __restrict__ al_d) {
    const int NR = 8;
    __shared__ float xs[NR][D1];
    __shared__ float s_sc[D1], s_sh[D1];
    int n0 = blockIdx.x * NR;
    int j = threadIdx.x;  // 0..63
    s_sc[j] = scale[j];       s_sh[j] = shift[j];
    s_sc[j + 64] = scale[j + 64]; s_sh[j + 64] = shift[j + 64];
    __syncthreads();
    for (int t = threadIdx.x; t < NR * D1; t += blockDim.x) {
        int r = t >> 7, k = t & 127;
        int n = n0 + r;
        float raw = (n < NN) ? x[n * D1 + k] : 0.f;
        xs[r][k] = lrelu(raw * s_sc[k] + s_sh[k], 0.01f);
    }
    __syncthreads();
    float acc[NR];
#pragma unroll
    for (int r = 0; r < NR; r++) acc[r] = 0.f;
    for (int k = 0; k < D1; k++) {
        float w = W[k * D2 + j];
#pragma unroll
        for (int r = 0; r < NR; r++) acc[r] += xs[r][k] * w;
    }
    float asj = as[j], adj = ad[j];
#pragma unroll
    for (int r = 0; r < NR; r++) {
        int n = n0 + r;
        if (n >= NN) break;
        xw[n * D2 + j] = acc[r];
        float vs = acc[r] * asj, vd = acc[r] * adj;
#pragma unroll
        for (int m = 32; m >= 1; m >>= 1) { vs += __shfl_xor(vs, m); vd += __shfl_xor(vd, m); }
        if (j == 0) { al_s[n] = vs; al_d[n] = vd; }
    }
}

// ---------------- fused GAT layer 2: one wave per destination ----------------
__global__ void k_gat2(const int* __restrict__ row_ptr, const u16* __restrict__ csr_src,
                       const float* __restrict__ als, const float* __restrict__ ald,
                       const float* __restrict__ xw, float* __restrict__ out) {
    const int d = blockIdx.x;
    const int beg = row_ptr[d];
    const int deg = row_ptr[d + 1] - beg;
    const int lane = threadIdx.x;  // 64

    __shared__ int   s_src[64];
    __shared__ float s_al[64];

    const float add = ald[d];

    float sm = 0.f;
    for (int i = lane; i < deg; i += 64) {
        int s = csr_src[beg + i];
        sm += __expf(lrelu(als[s] + add, 0.2f));
    }
#pragma unroll
    for (int m = 32; m >= 1; m >>= 1) sm += __shfl_xor(sm, m);
    const float z = 1.f / (sm + 1e-16f);

    float acc = 0.f;
    for (int base = 0; base < deg; base += 64) {
        int cnt = min(64, deg - base);
        if (lane < cnt) {
            int s = csr_src[beg + base + lane];
            s_src[lane] = s;
            s_al[lane] = __expf(lrelu(als[s] + add, 0.2f)) * z;
        }
        __syncthreads();
#pragma unroll 4
        for (int i = 0; i < cnt; i++)
            acc += s_al[i] * xw[s_src[i] * D2 + lane];
        __syncthreads();
    }
    out[d * D2 + lane] = acc;
}

extern "C" void kernel_launch(void* const* d_in, const int* in_sizes, int n_in,
                              void* d_out, int out_size, void* d_ws, size_t ws_size,
                              hipStream_t stream) {
    const float* x   = (const float*)d_in[0];
    const int*   ei  = (const int*)d_in[2];
    const float* W1  = (const float*)d_in[3];
    const float* as1 = (const float*)d_in[4];
    const float* ad1 = (const float*)d_in[5];
    const float* g1  = (const float*)d_in[7];
    const float* be1 = (const float*)d_in[8];
    const float* W2  = (const float*)d_in[9];
    const float* as2 = (const float*)d_in[10];
    const float* ad2 = (const float*)d_in[11];
    const float* g2  = (const float*)d_in[13];
    const float* be2 = (const float*)d_in[14];
    float* out = (float*)d_out;

    float* ws = (float*)d_ws;
    // Packed layout — identical footprint to R3 (proven < ws_size).
    float* xw1   = ws;                   // [0, 6.4M) floats; layer-1 only
    float* xw2   = ws;                   // [0, 3.2M)  reuses dead xw1 region
    float* al_s2 = ws + 3200000;         // 50k  (inside dead xw1 region)
    float* al_d2 = ws + 3250000;         // 50k  (inside dead xw1 region)
    float* al_s1 = ws + 6400000;         // 200k
    float* al_d1 = al_s1 + 200000;       // 200k
    float* agg1  = al_d1 + 200000;       // 6.4M
    int*   row_ptr = (int*)(agg1 + 6400000);  // 50,001 ints
    int*   cur     = row_ptr + 50001;         // 50,000 ints
    int*   part    = cur + 50000;             // 196 ints
    float* st      = (float*)(part + 196);    // 768 floats
    u16*   csr_src = (u16*)(st + 768);        // 850,000 u16

    // st layout: [0]=sum1 [128]=sq1 [256]=scale1 [384]=shift1
    //            [512]=sum2 [576]=sq2 [640]=scale2 [704]=shift2

    hipMemsetAsync(cur, 0, (size_t)NN * sizeof(int), stream);
    hipMemsetAsync(st, 0, 768 * sizeof(float), stream);

    // ---- CSR build ----
    k_hist<<<(ET + 255) / 256, 256, 0, stream>>>(ei, cur);
    k_blocksum<<<NB_SCAN, 256, 0, stream>>>(cur, part);
    k_scanpart<<<1, 256, 0, stream>>>(part);
    k_scanfinal<<<NB_SCAN, 256, 0, stream>>>(cur, part, row_ptr, cur);
    k_fill<<<(ET + 255) / 256, 256, 0, stream>>>(ei, cur, csr_src);

    // ---- layer 1 ----
    k_gemm1<<<(NN + 7) / 8, 128, 0, stream>>>(x, W1, as1, ad1, xw1, al_s1, al_d1);
    k_gat1<<<NN, 64, 0, stream>>>(row_ptr, csr_src, al_s1, al_d1, xw1, agg1);
    k_bnstats<D1><<<1024, D1, 0, stream>>>(agg1, st, st + 128);
    k_bnfinal<<<1, D1, 0, stream>>>(st, st + 128, g1, be1, st + 256, st + 384);

    // ---- layer 2 (BN1 apply fused into gemm2 staging) ----
    k_gemm2<<<(NN + 7) / 8, 64, 0, stream>>>(agg1, st + 256, st + 384, W2, as2, ad2, xw2, al_s2, al_d2);
    k_gat2<<<NN, 64, 0, stream>>>(row_ptr, csr_src, al_s2, al_d2, xw2, out);
    k_bnstats<D2><<<1024, D2, 0, stream>>>(out, st + 512, st + 576);
    k_bnfinal<<<1, D2, 0, stream>>>(st + 512, st + 576, g2, be2, st + 640, st + 704);
    k_bnapply2<<<(NN * D2 / 4 + 255) / 256, 256, 0, stream>>>(out, st + 640, st + 704, out);
}

// Round 5
// 367.650 us; speedup vs baseline: 6.8975x; 1.0478x over previous
//
#include <hip/hip_runtime.h>
#include <hip/hip_fp16.h>

#define NN 50000        // nodes
#define NE 800000       // edges (without self loops)
#define ET 850000       // edges + self loops
#define GD 128          // input feature dim
#define D1 128          // HEADS*H1
#define NH 4            // heads layer 1
#define D2 64           // layer-2 dim
#define NB_SCAN 196     // ceil(NN/256)
#define NBP 256         // bn partial blocks

typedef unsigned short u16;

__device__ __forceinline__ float lrelu(float x, float s) { return x > 0.f ? x : s * x; }

__device__ __forceinline__ void edge_sd(int e, const int* __restrict__ ei, int& s, int& d) {
    if (e < NE) { s = ei[e]; d = ei[NE + e]; }
    else { s = e - NE; d = s; }
}

// ---------------- CSR build ----------------
__global__ void k_hist(const int* __restrict__ ei, int* __restrict__ cnt) {
    int e = blockIdx.x * blockDim.x + threadIdx.x;
    if (e >= ET) return;
    int s, d; edge_sd(e, ei, s, d);
    atomicAdd(&cnt[d], 1);
}

__global__ void k_blocksum(const int* __restrict__ cnt, int* __restrict__ part) {
    __shared__ int r[256];
    int t = threadIdx.x, i = blockIdx.x * 256 + t;
    r[t] = (i < NN) ? cnt[i] : 0;
    __syncthreads();
    for (int s = 128; s >= 1; s >>= 1) {
        if (t < s) r[t] += r[t + s];
        __syncthreads();
    }
    if (t == 0) part[blockIdx.x] = r[0];
}

__global__ void k_scanpart(int* __restrict__ part) {  // exclusive, one block of 256
    __shared__ int r[256];
    int t = threadIdx.x;
    r[t] = (t < NB_SCAN) ? part[t] : 0;
    __syncthreads();
    for (int off = 1; off < 256; off <<= 1) {
        int v = (t >= off) ? r[t - off] : 0;
        __syncthreads();
        r[t] += v;
        __syncthreads();
    }
    if (t < NB_SCAN) part[t] = t ? r[t - 1] : 0;
}

__global__ void k_scanfinal(const int* __restrict__ cnt, const int* __restrict__ part,
                            int* __restrict__ row_ptr, int* __restrict__ cur) {
    __shared__ int r[256];
    int b = blockIdx.x, t = threadIdx.x, i = b * 256 + t;
    int v = (i < NN) ? cnt[i] : 0;
    r[t] = v;
    __syncthreads();
    for (int off = 1; off < 256; off <<= 1) {
        int u = (t >= off) ? r[t - off] : 0;
        __syncthreads();
        r[t] += u;
        __syncthreads();
    }
    if (i < NN) {
        int rp = part[b] + (t ? r[t - 1] : 0);
        row_ptr[i] = rp;
        cur[i] = rp;
    }
    if (i == NN - 1) row_ptr[NN] = part[b] + r[t];
}

__global__ void k_fill(const int* __restrict__ ei, int* __restrict__ cur, u16* __restrict__ csr_src) {
    int e = blockIdx.x * blockDim.x + threadIdx.x;
    if (e >= ET) return;
    int s, d; edge_sd(e, ei, s, d);
    int pos = atomicAdd(&cur[d], 1);
    csr_src[pos] = (u16)s;
}

// ---------------- GEMM1: xw1 = x @ W1 (fp16 out), plus per-head attention dots ----------------
__global__ void k_gemm1(const float* __restrict__ x, const float* __restrict__ W,
                        const float* __restrict__ as, const float* __restrict__ ad,
                        __half* __restrict__ xw, float* __restrict__ al_s, float* __restrict__ al_d) {
    const int NR = 8;                  // NN % 8 == 0, no tail guards
    __shared__ float xs[NR][GD];
    int n0 = blockIdx.x * NR;
    int j = threadIdx.x;  // 0..127
    const float4* xv = (const float4*)(x + (size_t)n0 * GD);
    float4* xsv = (float4*)&xs[0][0];
    xsv[j] = xv[j];
    xsv[j + 128] = xv[j + 128];
    __syncthreads();
    float acc[NR];
#pragma unroll
    for (int r = 0; r < NR; r++) acc[r] = 0.f;
    for (int k = 0; k < GD; k++) {
        float w = W[k * D1 + j];
#pragma unroll
        for (int r = 0; r < NR; r++) acc[r] += xs[r][k] * w;
    }
    int h = j >> 5, c = j & 31;
    float asj = as[j], adj = ad[j];
#pragma unroll
    for (int r = 0; r < NR; r++) {
        int n = n0 + r;
        xw[(size_t)n * D1 + j] = __float2half(acc[r]);
        float vs = acc[r] * asj, vd = acc[r] * adj;
#pragma unroll
        for (int m = 16; m >= 1; m >>= 1) { vs += __shfl_xor(vs, m); vd += __shfl_xor(vd, m); }
        if (c == 0) { al_s[n * NH + h] = vs; al_d[n * NH + h] = vd; }
    }
}

// ---------------- fused GAT layer 1: one wave per destination, single pass ----------------
__global__ void k_gat1(const int* __restrict__ row_ptr, const u16* __restrict__ csr_src,
                       const float* __restrict__ als, const float* __restrict__ ald,
                       const __half2* __restrict__ xw, float* __restrict__ out) {
    const int d = blockIdx.x;
    const int beg = row_ptr[d];
    const int deg = row_ptr[d + 1] - beg;
    const int lane = threadIdx.x;  // 64

    __shared__ int   s_src[64];
    __shared__ float s_al[64 * NH];

    const float4 adv = *(const float4*)(ald + d * NH);
    const int h = lane >> 4;  // head owning features (2*lane, 2*lane+1)

    // out = (sum_e w_e * xw[s_e]) / (sum_e w_e), w_e = exp(lrelu(logit))  [no max-shift
    // needed: logits are O(1); softmax is shift-invariant so this matches the reference]
    float ax = 0.f, ay = 0.f, den = 0.f;
    for (int base = 0; base < deg; base += 64) {
        int cnt = min(64, deg - base);
        if (lane < cnt) {
            int s = csr_src[beg + base + lane];
            s_src[lane] = s;
            const float4 a = *(const float4*)(als + s * NH);
            s_al[lane * NH + 0] = __expf(lrelu(a.x + adv.x, 0.2f));
            s_al[lane * NH + 1] = __expf(lrelu(a.y + adv.y, 0.2f));
            s_al[lane * NH + 2] = __expf(lrelu(a.z + adv.z, 0.2f));
            s_al[lane * NH + 3] = __expf(lrelu(a.w + adv.w, 0.2f));
        }
        __syncthreads();
#pragma unroll 4
        for (int i = 0; i < cnt; i++) {
            float al = s_al[i * NH + h];
            float2 v = __half22float2(xw[(size_t)s_src[i] * 64 + lane]);
            den += al; ax += al * v.x; ay += al * v.y;
        }
        __syncthreads();
    }
    float inv = 1.f / (den + 1e-16f);
    *(float2*)(out + (size_t)d * D1 + 2 * lane) = make_float2(ax * inv, ay * inv);
}

// ---------------- batchnorm: partial sums (no atomics) ----------------
template <int D>
__global__ void k_bnstats(const float* __restrict__ x, float* __restrict__ bp) {
    int j = threadIdx.x, bid = blockIdx.x;
    float s = 0.f, q = 0.f;
    for (int r = bid; r < NN; r += NBP) {
        float v = x[(size_t)r * D + j];
        s += v; q += v * v;
    }
    bp[bid * D + j] = s;
    bp[NBP * D + bid * D + j] = q;
}

// reduce partials + emit scale/shift (BN+affine folded to one FMA)
template <int D>
__global__ void k_bnreduce(const float* __restrict__ bp, const float* __restrict__ g,
                           const float* __restrict__ b, float* __restrict__ scale,
                           float* __restrict__ shift) {
    int j = threadIdx.x;
    float s = 0.f, q = 0.f;
    for (int i = 0; i < NBP; i++) {
        s += bp[i * D + j];
        q += bp[NBP * D + i * D + j];
    }
    float mu = s / (float)NN;
    float var = q / (float)NN - mu * mu;
    float sc = rsqrtf(var + 1e-5f) * g[j];
    scale[j] = sc;
    shift[j] = b[j] - mu * sc;
}

// final BN+lrelu for layer-2 output (float4)
__global__ void k_bnapply2(const float* __restrict__ x, const float* __restrict__ scale,
                           const float* __restrict__ shift, float* __restrict__ y) {
    int idx = blockIdx.x * blockDim.x + threadIdx.x;
    if (idx >= NN * D2 / 4) return;
    float4 v = ((const float4*)x)[idx];
    int c = (idx * 4) & (D2 - 1);
    v.x = lrelu(v.x * scale[c + 0] + shift[c + 0], 0.01f);
    v.y = lrelu(v.y * scale[c + 1] + shift[c + 1], 0.01f);
    v.z = lrelu(v.z * scale[c + 2] + shift[c + 2], 0.01f);
    v.w = lrelu(v.w * scale[c + 3] + shift[c + 3], 0.01f);
    ((float4*)y)[idx] = v;
}

// ---------------- GEMM2 with fused BN1-apply + lrelu, fp16 out ----------------
__global__ void k_gemm2(const float* __restrict__ x, const float* __restrict__ scale,
                        const float* __restrict__ shift, const float* __restrict__ W,
                        const float* __restrict__ as, const float* __restrict__ ad,
                        __half* __restrict__ xw, float* __restrict__ al_s, float* __restrict__ al_d) {
    const int NR = 8;
    __shared__ float xs[NR][D1];
    __shared__ float s_sc[D1], s_sh[D1];
    int n0 = blockIdx.x * NR;
    int j = threadIdx.x;  // 0..63
    s_sc[j] = scale[j];           s_sh[j] = shift[j];
    s_sc[j + 64] = scale[j + 64]; s_sh[j + 64] = shift[j + 64];
    __syncthreads();
    const float4* xv = (const float4*)(x + (size_t)n0 * D1);
    float4* xsv = (float4*)&xs[0][0];
#pragma unroll
    for (int t = j, it = 0; it < 4; t += 64, it++) {
        float4 v = xv[t];
        int k0 = (t & 31) * 4;
        v.x = lrelu(v.x * s_sc[k0 + 0] + s_sh[k0 + 0], 0.01f);
        v.y = lrelu(v.y * s_sc[k0 + 1] + s_sh[k0 + 1], 0.01f);
        v.z = lrelu(v.z * s_sc[k0 + 2] + s_sh[k0 + 2], 0.01f);
        v.w = lrelu(v.w * s_sc[k0 + 3] + s_sh[k0 + 3], 0.01f);
        xsv[t] = v;
    }
    __syncthreads();
    float acc[NR];
#pragma unroll
    for (int r = 0; r < NR; r++) acc[r] = 0.f;
    for (int k = 0; k < D1; k++) {
        float w = W[k * D2 + j];
#pragma unroll
        for (int r = 0; r < NR; r++) acc[r] += xs[r][k] * w;
    }
    float asj = as[j], adj = ad[j];
#pragma unroll
    for (int r = 0; r < NR; r++) {
        int n = n0 + r;
        xw[(size_t)n * D2 + j] = __float2half(acc[r]);
        float vs = acc[r] * asj, vd = acc[r] * adj;
#pragma unroll
        for (int m = 32; m >= 1; m >>= 1) { vs += __shfl_xor(vs, m); vd += __shfl_xor(vd, m); }
        if (j == 0) { al_s[n] = vs; al_d[n] = vd; }
    }
}

// ---------------- fused GAT layer 2: one wave per destination, register-only ----------------
__global__ void k_gat2(const int* __restrict__ row_ptr, const u16* __restrict__ csr_src,
                       const float* __restrict__ als, const float* __restrict__ ald,
                       const __half2* __restrict__ xw, float* __restrict__ out) {
    const int d = blockIdx.x;
    const int beg = row_ptr[d];
    const int deg = row_ptr[d + 1] - beg;
    const int lane = threadIdx.x;  // 64
    const int sub = lane >> 5, l = lane & 31;  // 2 edges per iter, 32 lanes each

    const float add = ald[d];
    float ax = 0.f, ay = 0.f, den = 0.f;
    for (int base = 0; base < deg; base += 64) {
        int cnt = min(64, deg - base);
        int s = 0; float e = 0.f;
        if (lane < cnt) {
            s = csr_src[beg + base + lane];
            e = __expf(lrelu(als[s] + add, 0.2f));
        }
        int np = (cnt + 1) >> 1;
        for (int i = 0; i < np; i++) {
            int idx = 2 * i + sub;                 // may hit cnt when odd: e=0 there, harmless
            float al = __shfl(e, idx);
            int  si  = __shfl(s, idx);
            float2 v = __half22float2(xw[(size_t)si * 32 + l]);
            den += al; ax += al * v.x; ay += al * v.y;
        }
    }
    ax += __shfl_xor(ax, 32); ay += __shfl_xor(ay, 32); den += __shfl_xor(den, 32);
    if (lane < 32) {
        float inv = 1.f / (den + 1e-16f);
        *(float2*)(out + (size_t)d * D2 + 2 * l) = make_float2(ax * inv, ay * inv);
    }
}

extern "C" void kernel_launch(void* const* d_in, const int* in_sizes, int n_in,
                              void* d_out, int out_size, void* d_ws, size_t ws_size,
                              hipStream_t stream) {
    const float* x   = (const float*)d_in[0];
    const int*   ei  = (const int*)d_in[2];
    const float* W1  = (const float*)d_in[3];
    const float* as1 = (const float*)d_in[4];
    const float* ad1 = (const float*)d_in[5];
    const float* g1  = (const float*)d_in[7];
    const float* be1 = (const float*)d_in[8];
    const float* W2  = (const float*)d_in[9];
    const float* as2 = (const float*)d_in[10];
    const float* ad2 = (const float*)d_in[11];
    const float* g2  = (const float*)d_in[13];
    const float* be2 = (const float*)d_in[14];
    float* out = (float*)d_out;

    float* ws = (float*)d_ws;
    // layout (float offsets); total footprint identical to R3/R4 (proven < ws_size)
    __half* xw1  = (__half*)ws;          // 6.4M halves = [0, 3.2M) floats; dead after gat1
    __half* xw2  = (__half*)ws;          // 3.2M halves = [0, 1.6M) floats (layer 2)
    float* bp    = ws + 1600000;         // 65,536 floats of BN partials (dead xw1 area)
    float* al_s2 = ws + 3200000;         // 50k
    float* al_d2 = ws + 3250000;         // 50k
    float* al_s1 = ws + 6400000;         // 200k
    float* al_d1 = al_s1 + 200000;       // 200k
    float* agg1  = al_d1 + 200000;       // 6.4M
    int*   row_ptr = (int*)(agg1 + 6400000);  // 50,001 ints
    int*   cur     = row_ptr + 50001;         // 50,000 ints
    int*   part    = cur + 50000;             // 196 ints
    float* st      = (float*)(part + 196);    // 384 floats: scale1,shift1,scale2,shift2
    u16*   csr_src = (u16*)(st + 768);        // 850,000 u16

    hipMemsetAsync(cur, 0, (size_t)NN * sizeof(int), stream);

    // ---- CSR build ----
    k_hist<<<(ET + 255) / 256, 256, 0, stream>>>(ei, cur);
    k_blocksum<<<NB_SCAN, 256, 0, stream>>>(cur, part);
    k_scanpart<<<1, 256, 0, stream>>>(part);
    k_scanfinal<<<NB_SCAN, 256, 0, stream>>>(cur, part, row_ptr, cur);
    k_fill<<<(ET + 255) / 256, 256, 0, stream>>>(ei, cur, csr_src);

    // ---- layer 1 ----
    k_gemm1<<<NN / 8, 128, 0, stream>>>(x, W1, as1, ad1, xw1, al_s1, al_d1);
    k_gat1<<<NN, 64, 0, stream>>>(row_ptr, csr_src, al_s1, al_d1, (const __half2*)xw1, agg1);
    k_bnstats<D1><<<NBP, D1, 0, stream>>>(agg1, bp);
    k_bnreduce<D1><<<1, D1, 0, stream>>>(bp, g1, be1, st, st + 128);

    // ---- layer 2 (BN1 apply fused into gemm2 staging) ----
    k_gemm2<<<NN / 8, 64, 0, stream>>>(agg1, st, st + 128, W2, as2, ad2, xw2, al_s2, al_d2);
    k_gat2<<<NN, 64, 0, stream>>>(row_ptr, csr_src, al_s2, al_d2, (const __half2*)xw2, out);
    k_bnstats<D2><<<NBP, D2, 0, stream>>>(out, bp);
    k_bnreduce<D2><<<1, D2, 0, stream>>>(bp, g2, be2, st + 256, st + 320);
    k_bnapply2<<<(NN * D2 / 4 + 255) / 256, 256, 0, stream>>>(out, st + 256, st + 320, out);
}

// Round 6
// 240.787 us; speedup vs baseline: 10.5316x; 1.5269x over previous
//
#include <hip/hip_runtime.h>
#include <hip/hip_fp16.h>

#define NN 50000        // nodes
#define NE 800000       // edges (without self loops)
#define ET 850000       // edges + self loops
#define GD 128          // input feature dim
#define D1 128          // HEADS*H1
#define NH 4            // heads layer 1
#define D2 64           // layer-2 dim
#define NB_SCAN 196     // ceil(NN/256)
#define NBP 1024        // bn partial blocks

typedef unsigned short u16;
typedef _Float16 half8_t __attribute__((ext_vector_type(8)));
typedef float    f32x4_t __attribute__((ext_vector_type(4)));

__device__ __forceinline__ float lrelu(float x, float s) { return x > 0.f ? x : s * x; }

__device__ __forceinline__ void edge_sd(int e, const int* __restrict__ ei, int& s, int& d) {
    if (e < NE) { s = ei[e]; d = ei[NE + e]; }
    else { s = e - NE; d = s; }
}

// ---------------- CSR build ----------------
__global__ void k_hist(const int* __restrict__ ei, int* __restrict__ cnt) {
    int e = blockIdx.x * blockDim.x + threadIdx.x;
    if (e >= ET) return;
    int s, d; edge_sd(e, ei, s, d);
    atomicAdd(&cnt[d], 1);
}

__global__ void k_blocksum(const int* __restrict__ cnt, int* __restrict__ part) {
    __shared__ int r[256];
    int t = threadIdx.x, i = blockIdx.x * 256 + t;
    r[t] = (i < NN) ? cnt[i] : 0;
    __syncthreads();
    for (int s = 128; s >= 1; s >>= 1) {
        if (t < s) r[t] += r[t + s];
        __syncthreads();
    }
    if (t == 0) part[blockIdx.x] = r[0];
}

__global__ void k_scanpart(int* __restrict__ part) {
    __shared__ int r[256];
    int t = threadIdx.x;
    r[t] = (t < NB_SCAN) ? part[t] : 0;
    __syncthreads();
    for (int off = 1; off < 256; off <<= 1) {
        int v = (t >= off) ? r[t - off] : 0;
        __syncthreads();
        r[t] += v;
        __syncthreads();
    }
    if (t < NB_SCAN) part[t] = t ? r[t - 1] : 0;
}

__global__ void k_scanfinal(const int* __restrict__ cnt, const int* __restrict__ part,
                            int* __restrict__ row_ptr, int* __restrict__ cur) {
    __shared__ int r[256];
    int b = blockIdx.x, t = threadIdx.x, i = b * 256 + t;
    int v = (i < NN) ? cnt[i] : 0;
    r[t] = v;
    __syncthreads();
    for (int off = 1; off < 256; off <<= 1) {
        int u = (t >= off) ? r[t - off] : 0;
        __syncthreads();
        r[t] += u;
        __syncthreads();
    }
    if (i < NN) {
        int rp = part[b] + (t ? r[t - 1] : 0);
        row_ptr[i] = rp;
        cur[i] = rp;
    }
    if (i == NN - 1) row_ptr[NN] = part[b] + r[t];
}

__global__ void k_fill(const int* __restrict__ ei, int* __restrict__ cur, u16* __restrict__ csr_src) {
    int e = blockIdx.x * blockDim.x + threadIdx.x;
    if (e >= ET) return;
    int s, d; edge_sd(e, ei, s, d);
    int pos = atomicAdd(&cur[d], 1);
    csr_src[pos] = (u16)s;
}

// ---------------- weight permute+cvt for MFMA B-fragments ----------------
// Wp[( kk*NT + nt )*64 + l][i] = W[(kk*32 + (l>>4)*8 + i) * N + nt*16 + (l&15)]
__global__ void k_prepw(const float* __restrict__ W1, const float* __restrict__ W2,
                        __half* __restrict__ Wp1, __half* __restrict__ Wp2) {
    int idx = blockIdx.x * 256 + threadIdx.x;
    if (idx < 16384) {
        int i = idx & 7, l = (idx >> 3) & 63, nt = (idx >> 9) & 7, kk = idx >> 12;
        int k = kk * 32 + (l >> 4) * 8 + i, n = nt * 16 + (l & 15);
        Wp1[idx] = __float2half(W1[k * D1 + n]);
    } else if (idx < 24576) {
        int x2 = idx - 16384;
        int i = x2 & 7, l = (x2 >> 3) & 63, nt = (x2 >> 9) & 3, kk = x2 >> 11;
        int k = kk * 32 + (l >> 4) * 8 + i, n = nt * 16 + (l & 15);
        Wp2[x2] = __float2half(W2[k * D2 + n]);
    }
}

// ---------------- GEMM1 via MFMA: one wave per 16-row strip ----------------
__global__ void k_gemm1m(const float* __restrict__ x, const half8_t* __restrict__ wp,
                         const float* __restrict__ as, const float* __restrict__ ad,
                         __half* __restrict__ xw, float* __restrict__ al_s, float* __restrict__ al_d) {
    const int l = threadIdx.x;           // 64
    const int row0 = blockIdx.x * 16;    // 3125 blocks
    const int c = l & 15, g = l >> 4;
    const float* xrow = x + (size_t)(row0 + c) * GD;

    f32x4_t acc[8];
#pragma unroll
    for (int nt = 0; nt < 8; nt++) acc[nt] = (f32x4_t){0.f, 0.f, 0.f, 0.f};

#pragma unroll
    for (int kk = 0; kk < 4; kk++) {
        const int koff = kk * 32 + g * 8;
        f32x4_t a0 = *(const f32x4_t*)(xrow + koff);
        f32x4_t a1 = *(const f32x4_t*)(xrow + koff + 4);
        half8_t af;
#pragma unroll
        for (int i = 0; i < 4; i++) { af[i] = (_Float16)a0[i]; af[i + 4] = (_Float16)a1[i]; }
#pragma unroll
        for (int nt = 0; nt < 8; nt++) {
            half8_t bf = wp[(kk * 8 + nt) * 64 + l];
            acc[nt] = __builtin_amdgcn_mfma_f32_16x16x32_f16(af, bf, acc[nt], 0, 0, 0);
        }
    }

    float asv[8], adv[8];
#pragma unroll
    for (int nt = 0; nt < 8; nt++) { asv[nt] = as[nt * 16 + c]; adv[nt] = ad[nt * 16 + c]; }

#pragma unroll
    for (int r = 0; r < 4; r++) {
        const int row = row0 + g * 4 + r;
        __half* xwr = xw + (size_t)row * D1;
        float hs[4] = {0.f, 0.f, 0.f, 0.f}, hd[4] = {0.f, 0.f, 0.f, 0.f};
#pragma unroll
        for (int nt = 0; nt < 8; nt++) {
            float v = acc[nt][r];
            xwr[nt * 16 + c] = __float2half(v);
            hs[nt >> 1] += v * asv[nt];
            hd[nt >> 1] += v * adv[nt];
        }
#pragma unroll
        for (int m = 1; m <= 8; m <<= 1) {
#pragma unroll
            for (int h = 0; h < 4; h++) { hs[h] += __shfl_xor(hs[h], m); hd[h] += __shfl_xor(hd[h], m); }
        }
        if (c == 0) {
#pragma unroll
            for (int h = 0; h < 4; h++) { al_s[row * NH + h] = hs[h]; al_d[row * NH + h] = hd[h]; }
        }
    }
}

// ---------------- fused GAT layer 1: one wave per destination, single pass ----------------
__global__ void k_gat1(const int* __restrict__ row_ptr, const u16* __restrict__ csr_src,
                       const float* __restrict__ als, const float* __restrict__ ald,
                       const __half2* __restrict__ xw, float* __restrict__ out) {
    const int d = blockIdx.x;
    const int beg = row_ptr[d];
    const int deg = row_ptr[d + 1] - beg;
    const int lane = threadIdx.x;  // 64

    __shared__ int   s_src[64];
    __shared__ float s_al[64 * NH];

    const float4 adv = *(const float4*)(ald + d * NH);
    const int h = lane >> 4;

    float ax = 0.f, ay = 0.f, den = 0.f;
    for (int base = 0; base < deg; base += 64) {
        int cnt = min(64, deg - base);
        if (lane < cnt) {
            int s = csr_src[beg + base + lane];
            s_src[lane] = s;
            const float4 a = *(const float4*)(als + s * NH);
            s_al[lane * NH + 0] = __expf(lrelu(a.x + adv.x, 0.2f));
            s_al[lane * NH + 1] = __expf(lrelu(a.y + adv.y, 0.2f));
            s_al[lane * NH + 2] = __expf(lrelu(a.z + adv.z, 0.2f));
            s_al[lane * NH + 3] = __expf(lrelu(a.w + adv.w, 0.2f));
        }
        __syncthreads();
#pragma unroll 4
        for (int i = 0; i < cnt; i++) {
            float al = s_al[i * NH + h];
            float2 v = __half22float2(xw[(size_t)s_src[i] * 64 + lane]);
            den += al; ax += al * v.x; ay += al * v.y;
        }
        __syncthreads();
    }
    float inv = 1.f / (den + 1e-16f);
    *(float2*)(out + (size_t)d * D1 + 2 * lane) = make_float2(ax * inv, ay * inv);
}

// ---------------- batchnorm: partials, parallel reduce ----------------
template <int D>
__global__ void k_bnstats(const float* __restrict__ x, float* __restrict__ bp) {
    int j = threadIdx.x, bid = blockIdx.x;
    float s = 0.f, q = 0.f;
    for (int r = bid; r < NN; r += NBP) {
        float v = x[(size_t)r * D + j];
        s += v; q += v * v;
    }
    bp[bid * D + j] = s;
    bp[NBP * D + bid * D + j] = q;
}

template <int D>
__global__ void k_bnreduce(const float* __restrict__ bp, const float* __restrict__ g,
                           const float* __restrict__ b, float* __restrict__ scale,
                           float* __restrict__ shift) {
    __shared__ float rs[256], rq[256];
    int j = blockIdx.x, t = threadIdx.x;
    float s = 0.f, q = 0.f;
    for (int i = t; i < NBP; i += 256) {
        s += bp[i * D + j];
        q += bp[NBP * D + i * D + j];
    }
    rs[t] = s; rq[t] = q;
    __syncthreads();
    for (int st = 128; st >= 1; st >>= 1) {
        if (t < st) { rs[t] += rs[t + st]; rq[t] += rq[t + st]; }
        __syncthreads();
    }
    if (t == 0) {
        float mu = rs[0] / (float)NN;
        float var = rq[0] / (float)NN - mu * mu;
        float sc = rsqrtf(var + 1e-5f) * g[j];
        scale[j] = sc;
        shift[j] = b[j] - mu * sc;
    }
}

// final BN+lrelu for layer-2 output (float4)
__global__ void k_bnapply2(const float* __restrict__ x, const float* __restrict__ scale,
                           const float* __restrict__ shift, float* __restrict__ y) {
    int idx = blockIdx.x * blockDim.x + threadIdx.x;
    if (idx >= NN * D2 / 4) return;
    float4 v = ((const float4*)x)[idx];
    int c = (idx * 4) & (D2 - 1);
    v.x = lrelu(v.x * scale[c + 0] + shift[c + 0], 0.01f);
    v.y = lrelu(v.y * scale[c + 1] + shift[c + 1], 0.01f);
    v.z = lrelu(v.z * scale[c + 2] + shift[c + 2], 0.01f);
    v.w = lrelu(v.w * scale[c + 3] + shift[c + 3], 0.01f);
    ((float4*)y)[idx] = v;
}

// ---------------- GEMM2 via MFMA with fused BN1-apply + lrelu ----------------
__global__ void k_gemm2m(const float* __restrict__ x, const float* __restrict__ scale,
                         const float* __restrict__ shift, const half8_t* __restrict__ wp,
                         const float* __restrict__ as, const float* __restrict__ ad,
                         __half* __restrict__ xw, float* __restrict__ al_s, float* __restrict__ al_d) {
    const int l = threadIdx.x;
    const int row0 = blockIdx.x * 16;
    const int c = l & 15, g = l >> 4;
    const float* xrow = x + (size_t)(row0 + c) * D1;

    f32x4_t acc[4];
#pragma unroll
    for (int nt = 0; nt < 4; nt++) acc[nt] = (f32x4_t){0.f, 0.f, 0.f, 0.f};

#pragma unroll
    for (int kk = 0; kk < 4; kk++) {
        const int koff = kk * 32 + g * 8;
        f32x4_t a0 = *(const f32x4_t*)(xrow + koff);
        f32x4_t a1 = *(const f32x4_t*)(xrow + koff + 4);
        f32x4_t sc0 = *(const f32x4_t*)(scale + koff);
        f32x4_t sc1 = *(const f32x4_t*)(scale + koff + 4);
        f32x4_t sh0 = *(const f32x4_t*)(shift + koff);
        f32x4_t sh1 = *(const f32x4_t*)(shift + koff + 4);
        half8_t af;
#pragma unroll
        for (int i = 0; i < 4; i++) {
            af[i]     = (_Float16)lrelu(a0[i] * sc0[i] + sh0[i], 0.01f);
            af[i + 4] = (_Float16)lrelu(a1[i] * sc1[i] + sh1[i], 0.01f);
        }
#pragma unroll
        for (int nt = 0; nt < 4; nt++) {
            half8_t bf = wp[(kk * 4 + nt) * 64 + l];
            acc[nt] = __builtin_amdgcn_mfma_f32_16x16x32_f16(af, bf, acc[nt], 0, 0, 0);
        }
    }

    float asv[4], adv[4];
#pragma unroll
    for (int nt = 0; nt < 4; nt++) { asv[nt] = as[nt * 16 + c]; adv[nt] = ad[nt * 16 + c]; }

#pragma unroll
    for (int r = 0; r < 4; r++) {
        const int row = row0 + g * 4 + r;
        __half* xwr = xw + (size_t)row * D2;
        float hs = 0.f, hd = 0.f;
#pragma unroll
        for (int nt = 0; nt < 4; nt++) {
            float v = acc[nt][r];
            xwr[nt * 16 + c] = __float2half(v);
            hs += v * asv[nt];
            hd += v * adv[nt];
        }
#pragma unroll
        for (int m = 1; m <= 8; m <<= 1) { hs += __shfl_xor(hs, m); hd += __shfl_xor(hd, m); }
        if (c == 0) { al_s[row] = hs; al_d[row] = hd; }
    }
}

// ---------------- fused GAT layer 2: one wave per destination, register-only ----------------
__global__ void k_gat2(const int* __restrict__ row_ptr, const u16* __restrict__ csr_src,
                       const float* __restrict__ als, const float* __restrict__ ald,
                       const __half2* __restrict__ xw, float* __restrict__ out) {
    const int d = blockIdx.x;
    const int beg = row_ptr[d];
    const int deg = row_ptr[d + 1] - beg;
    const int lane = threadIdx.x;
    const int sub = lane >> 5, l = lane & 31;

    const float add = ald[d];
    float ax = 0.f, ay = 0.f, den = 0.f;
    for (int base = 0; base < deg; base += 64) {
        int cnt = min(64, deg - base);
        int s = 0; float e = 0.f;
        if (lane < cnt) {
            s = csr_src[beg + base + lane];
            e = __expf(lrelu(als[s] + add, 0.2f));
        }
        int np = (cnt + 1) >> 1;
        for (int i = 0; i < np; i++) {
            int idx = 2 * i + sub;
            float al = __shfl(e, idx);
            int  si  = __shfl(s, idx);
            float2 v = __half22float2(xw[(size_t)si * 32 + l]);
            den += al; ax += al * v.x; ay += al * v.y;
        }
    }
    ax += __shfl_xor(ax, 32); ay += __shfl_xor(ay, 32); den += __shfl_xor(den, 32);
    if (lane < 32) {
        float inv = 1.f / (den + 1e-16f);
        *(float2*)(out + (size_t)d * D2 + 2 * l) = make_float2(ax * inv, ay * inv);
    }
}

extern "C" void kernel_launch(void* const* d_in, const int* in_sizes, int n_in,
                              void* d_out, int out_size, void* d_ws, size_t ws_size,
                              hipStream_t stream) {
    const float* x   = (const float*)d_in[0];
    const int*   ei  = (const int*)d_in[2];
    const float* W1  = (const float*)d_in[3];
    const float* as1 = (const float*)d_in[4];
    const float* ad1 = (const float*)d_in[5];
    const float* g1  = (const float*)d_in[7];
    const float* be1 = (const float*)d_in[8];
    const float* W2  = (const float*)d_in[9];
    const float* as2 = (const float*)d_in[10];
    const float* ad2 = (const float*)d_in[11];
    const float* g2  = (const float*)d_in[13];
    const float* be2 = (const float*)d_in[14];
    float* out = (float*)d_out;

    float* ws = (float*)d_ws;
    // layout (float offsets); total ≈54.95 MB < proven capacity
    __half* xw1  = (__half*)ws;          // 6.4M halves; dead after gat1
    __half* xw2  = (__half*)ws;          // 3.2M halves (layer 2)
    float* bp    = ws + 1600000;         // 2*NBP*128 = 262144 floats max (dead-xw1 area)
    float* al_s2 = ws + 3200000;         // 50k
    float* al_d2 = ws + 3250000;         // 50k
    float* al_s1 = ws + 6400000;         // 200k
    float* al_d1 = al_s1 + 200000;       // 200k
    float* agg1  = al_d1 + 200000;       // 6.4M
    int*   row_ptr = (int*)(agg1 + 6400000);  // 50,001 ints
    int*   cur     = row_ptr + 50001;         // 50,000 ints
    int*   part    = cur + 50000;             // 199 ints (pad for 16B-aligned st)
    float* st      = (float*)(part + 199);    // 384 floats: scale1,shift1,scale2,shift2
    u16*   csr_src = (u16*)(st + 768);        // 850,000 u16
    __half* Wp1    = (__half*)(csr_src + 850000);  // 16384 halves, 16B-aligned
    __half* Wp2    = Wp1 + 16384;                  // 8192 halves

    hipMemsetAsync(cur, 0, (size_t)NN * sizeof(int), stream);

    // ---- CSR build + weight prep ----
    k_prepw<<<96, 256, 0, stream>>>(W1, W2, Wp1, Wp2);
    k_hist<<<(ET + 255) / 256, 256, 0, stream>>>(ei, cur);
    k_blocksum<<<NB_SCAN, 256, 0, stream>>>(cur, part);
    k_scanpart<<<1, 256, 0, stream>>>(part);
    k_scanfinal<<<NB_SCAN, 256, 0, stream>>>(cur, part, row_ptr, cur);
    k_fill<<<(ET + 255) / 256, 256, 0, stream>>>(ei, cur, csr_src);

    // ---- layer 1 ----
    k_gemm1m<<<NN / 16, 64, 0, stream>>>(x, (const half8_t*)Wp1, as1, ad1, xw1, al_s1, al_d1);
    k_gat1<<<NN, 64, 0, stream>>>(row_ptr, csr_src, al_s1, al_d1, (const __half2*)xw1, agg1);
    k_bnstats<D1><<<NBP, D1, 0, stream>>>(agg1, bp);
    k_bnreduce<D1><<<D1, 256, 0, stream>>>(bp, g1, be1, st, st + 128);

    // ---- layer 2 (BN1 apply fused into gemm2's A-read) ----
    k_gemm2m<<<NN / 16, 64, 0, stream>>>(agg1, st, st + 128, (const half8_t*)Wp2, as2, ad2, xw2, al_s2, al_d2);
    k_gat2<<<NN, 64, 0, stream>>>(row_ptr, csr_src, al_s2, al_d2, (const __half2*)xw2, out);
    k_bnstats<D2><<<NBP, D2, 0, stream>>>(out, bp);
    k_bnreduce<D2><<<D2, 256, 0, stream>>>(bp, g2, be2, st + 256, st + 320);
    k_bnapply2<<<(NN * D2 / 4 + 255) / 256, 256, 0, stream>>>(out, st + 256, st + 320, out);
}

// Round 7
// 227.812 us; speedup vs baseline: 11.1314x; 1.0570x over previous
//
#include <hip/hip_runtime.h>
#include <hip/hip_fp16.h>

#define NN 50000        // nodes
#define NE 800000       // edges (without self loops)
#define ET 850000       // edges + self loops
#define GD 128          // input feature dim
#define D1 128          // HEADS*H1
#define NH 4            // heads layer 1
#define D2 64           // layer-2 dim
#define NB_SCAN 196     // ceil(NN/256)
#define NBP 1024        // bn partial blocks
#define NXCD 8
#define NPX 6250        // nodes per XCD shard

typedef unsigned short u16;
typedef _Float16 half8_t __attribute__((ext_vector_type(8)));
typedef float    f32x4_t __attribute__((ext_vector_type(4)));

__device__ __forceinline__ float lrelu(float x, float s) { return x > 0.f ? x : s * x; }

// ---------------- fused init: zero counters + permute/cvt weights ----------------
// Wp[( kk*NT + nt )*64 + l][i] = W[(kk*32 + (l>>4)*8 + i) * N + nt*16 + (l&15)]
__global__ void k_prepw(const float* __restrict__ W1, const float* __restrict__ W2,
                        __half* __restrict__ Wp1, __half* __restrict__ Wp2,
                        int* __restrict__ cur) {
    int idx = blockIdx.x * 256 + threadIdx.x;
    if (idx < NN) cur[idx] = 0;
    if (idx < 16384) {
        int i = idx & 7, l = (idx >> 3) & 63, nt = (idx >> 9) & 7, kk = idx >> 12;
        int k = kk * 32 + (l >> 4) * 8 + i, n = nt * 16 + (l & 15);
        Wp1[idx] = __float2half(W1[k * D1 + n]);
    } else if (idx < 24576) {
        int x2 = idx - 16384;
        int i = x2 & 7, l = (x2 >> 3) & 63, nt = (x2 >> 9) & 3, kk = x2 >> 11;
        int k = kk * 32 + (l >> 4) * 8 + i, n = nt * 16 + (l & 15);
        Wp2[x2] = __float2half(W2[k * D2 + n]);
    }
}

// ---------------- CSR build: XCD-sharded hist & fill ----------------
// blockIdx%8 presumed XCD id (perf heuristic only): each XCD group scans all
// edges but processes only dst in its shard -> counters + csr region stay in
// that XCD's L2 (no cross-XCD line ping-pong).
__global__ void k_hist_x(const int* __restrict__ ei, int* __restrict__ cnt) {
    const int xcd = blockIdx.x & (NXCD - 1);
    const int grp = blockIdx.x >> 3;
    const int ngrp = gridDim.x >> 3;
    const int lo = xcd * NPX, hi = lo + NPX;
    for (int e = grp * 256 + threadIdx.x; e < ET; e += ngrp * 256) {
        int d = (e < NE) ? ei[NE + e] : (e - NE);
        if (d >= lo && d < hi) atomicAdd(&cnt[d], 1);
    }
}

__global__ void k_fill_x(const int* __restrict__ ei, int* __restrict__ cur,
                         u16* __restrict__ csr_src) {
    const int xcd = blockIdx.x & (NXCD - 1);
    const int grp = blockIdx.x >> 3;
    const int ngrp = gridDim.x >> 3;
    const int lo = xcd * NPX, hi = lo + NPX;
    for (int e = grp * 256 + threadIdx.x; e < ET; e += ngrp * 256) {
        int d = (e < NE) ? ei[NE + e] : (e - NE);
        if (d >= lo && d < hi) {
            int s = (e < NE) ? ei[e] : d;
            int pos = atomicAdd(&cur[d], 1);
            csr_src[pos] = (u16)s;
        }
    }
}

__global__ void k_blocksum(const int* __restrict__ cnt, int* __restrict__ part) {
    __shared__ int r[256];
    int t = threadIdx.x, i = blockIdx.x * 256 + t;
    r[t] = (i < NN) ? cnt[i] : 0;
    __syncthreads();
    for (int s = 128; s >= 1; s >>= 1) {
        if (t < s) r[t] += r[t + s];
        __syncthreads();
    }
    if (t == 0) part[blockIdx.x] = r[0];
}

__global__ void k_scanpart(int* __restrict__ part) {
    __shared__ int r[256];
    int t = threadIdx.x;
    r[t] = (t < NB_SCAN) ? part[t] : 0;
    __syncthreads();
    for (int off = 1; off < 256; off <<= 1) {
        int v = (t >= off) ? r[t - off] : 0;
        __syncthreads();
        r[t] += v;
        __syncthreads();
    }
    if (t < NB_SCAN) part[t] = t ? r[t - 1] : 0;
}

__global__ void k_scanfinal(const int* __restrict__ cnt, const int* __restrict__ part,
                            int* __restrict__ row_ptr, int* __restrict__ cur) {
    __shared__ int r[256];
    int b = blockIdx.x, t = threadIdx.x, i = b * 256 + t;
    int v = (i < NN) ? cnt[i] : 0;
    r[t] = v;
    __syncthreads();
    for (int off = 1; off < 256; off <<= 1) {
        int u = (t >= off) ? r[t - off] : 0;
        __syncthreads();
        r[t] += u;
        __syncthreads();
    }
    if (i < NN) {
        int rp = part[b] + (t ? r[t - 1] : 0);
        row_ptr[i] = rp;
        cur[i] = rp;
    }
    if (i == NN - 1) row_ptr[NN] = part[b] + r[t];
}

// ---------------- GEMM1 via MFMA: one wave per 16-row strip ----------------
__global__ void k_gemm1m(const float* __restrict__ x, const half8_t* __restrict__ wp,
                         const float* __restrict__ as, const float* __restrict__ ad,
                         __half* __restrict__ xw, float* __restrict__ al_s, float* __restrict__ al_d) {
    const int l = threadIdx.x;           // 64
    const int row0 = blockIdx.x * 16;    // 3125 blocks
    const int c = l & 15, g = l >> 4;
    const float* xrow = x + (size_t)(row0 + c) * GD;

    f32x4_t acc[8];
#pragma unroll
    for (int nt = 0; nt < 8; nt++) acc[nt] = (f32x4_t){0.f, 0.f, 0.f, 0.f};

#pragma unroll
    for (int kk = 0; kk < 4; kk++) {
        const int koff = kk * 32 + g * 8;
        f32x4_t a0 = *(const f32x4_t*)(xrow + koff);
        f32x4_t a1 = *(const f32x4_t*)(xrow + koff + 4);
        half8_t af;
#pragma unroll
        for (int i = 0; i < 4; i++) { af[i] = (_Float16)a0[i]; af[i + 4] = (_Float16)a1[i]; }
#pragma unroll
        for (int nt = 0; nt < 8; nt++) {
            half8_t bf = wp[(kk * 8 + nt) * 64 + l];
            acc[nt] = __builtin_amdgcn_mfma_f32_16x16x32_f16(af, bf, acc[nt], 0, 0, 0);
        }
    }

    float asv[8], adv[8];
#pragma unroll
    for (int nt = 0; nt < 8; nt++) { asv[nt] = as[nt * 16 + c]; adv[nt] = ad[nt * 16 + c]; }

#pragma unroll
    for (int r = 0; r < 4; r++) {
        const int row = row0 + g * 4 + r;
        __half* xwr = xw + (size_t)row * D1;
        float hs[4] = {0.f, 0.f, 0.f, 0.f}, hd[4] = {0.f, 0.f, 0.f, 0.f};
#pragma unroll
        for (int nt = 0; nt < 8; nt++) {
            float v = acc[nt][r];
            xwr[nt * 16 + c] = __float2half(v);
            hs[nt >> 1] += v * asv[nt];
            hd[nt >> 1] += v * adv[nt];
        }
#pragma unroll
        for (int m = 1; m <= 8; m <<= 1) {
#pragma unroll
            for (int h = 0; h < 4; h++) { hs[h] += __shfl_xor(hs[h], m); hd[h] += __shfl_xor(hd[h], m); }
        }
        if (c == 0) {
#pragma unroll
            for (int h = 0; h < 4; h++) { al_s[row * NH + h] = hs[h]; al_d[row * NH + h] = hd[h]; }
        }
    }
}

// ---------------- fused GAT layer 1: one wave per destination, single pass ----------------
__global__ void k_gat1(const int* __restrict__ row_ptr, const u16* __restrict__ csr_src,
                       const float* __restrict__ als, const float* __restrict__ ald,
                       const __half2* __restrict__ xw, float* __restrict__ out) {
    const int d = blockIdx.x;
    const int beg = row_ptr[d];
    const int deg = row_ptr[d + 1] - beg;
    const int lane = threadIdx.x;  // 64

    __shared__ int   s_src[64];
    __shared__ float s_al[64 * NH];

    const float4 adv = *(const float4*)(ald + d * NH);
    const int h = lane >> 4;

    float ax = 0.f, ay = 0.f, den = 0.f;
    for (int base = 0; base < deg; base += 64) {
        int cnt = min(64, deg - base);
        if (lane < cnt) {
            int s = csr_src[beg + base + lane];
            s_src[lane] = s;
            const float4 a = *(const float4*)(als + s * NH);
            s_al[lane * NH + 0] = __expf(lrelu(a.x + adv.x, 0.2f));
            s_al[lane * NH + 1] = __expf(lrelu(a.y + adv.y, 0.2f));
            s_al[lane * NH + 2] = __expf(lrelu(a.z + adv.z, 0.2f));
            s_al[lane * NH + 3] = __expf(lrelu(a.w + adv.w, 0.2f));
        }
        __syncthreads();
#pragma unroll 4
        for (int i = 0; i < cnt; i++) {
            float al = s_al[i * NH + h];
            float2 v = __half22float2(xw[(size_t)s_src[i] * 64 + lane]);
            den += al; ax += al * v.x; ay += al * v.y;
        }
        __syncthreads();
    }
    float inv = 1.f / (den + 1e-16f);
    *(float2*)(out + (size_t)d * D1 + 2 * lane) = make_float2(ax * inv, ay * inv);
}

// ---------------- batchnorm: partials, parallel reduce ----------------
template <int D>
__global__ void k_bnstats(const float* __restrict__ x, float* __restrict__ bp) {
    int j = threadIdx.x, bid = blockIdx.x;
    float s = 0.f, q = 0.f;
    for (int r = bid; r < NN; r += NBP) {
        float v = x[(size_t)r * D + j];
        s += v; q += v * v;
    }
    bp[bid * D + j] = s;
    bp[NBP * D + bid * D + j] = q;
}

template <int D>
__global__ void k_bnreduce(const float* __restrict__ bp, const float* __restrict__ g,
                           const float* __restrict__ b, float* __restrict__ scale,
                           float* __restrict__ shift) {
    __shared__ float rs[256], rq[256];
    int j = blockIdx.x, t = threadIdx.x;
    float s = 0.f, q = 0.f;
    for (int i = t; i < NBP; i += 256) {
        s += bp[i * D + j];
        q += bp[NBP * D + i * D + j];
    }
    rs[t] = s; rq[t] = q;
    __syncthreads();
    for (int st = 128; st >= 1; st >>= 1) {
        if (t < st) { rs[t] += rs[t + st]; rq[t] += rq[t + st]; }
        __syncthreads();
    }
    if (t == 0) {
        float mu = rs[0] / (float)NN;
        float var = rq[0] / (float)NN - mu * mu;
        float sc = rsqrtf(var + 1e-5f) * g[j];
        scale[j] = sc;
        shift[j] = b[j] - mu * sc;
    }
}

// final BN+lrelu for layer-2 output (float4)
__global__ void k_bnapply2(const float* __restrict__ x, const float* __restrict__ scale,
                           const float* __restrict__ shift, float* __restrict__ y) {
    int idx = blockIdx.x * blockDim.x + threadIdx.x;
    if (idx >= NN * D2 / 4) return;
    float4 v = ((const float4*)x)[idx];
    int c = (idx * 4) & (D2 - 1);
    v.x = lrelu(v.x * scale[c + 0] + shift[c + 0], 0.01f);
    v.y = lrelu(v.y * scale[c + 1] + shift[c + 1], 0.01f);
    v.z = lrelu(v.z * scale[c + 2] + shift[c + 2], 0.01f);
    v.w = lrelu(v.w * scale[c + 3] + shift[c + 3], 0.01f);
    ((float4*)y)[idx] = v;
}

// ---------------- GEMM2 via MFMA with fused BN1-apply + lrelu ----------------
__global__ void k_gemm2m(const float* __restrict__ x, const float* __restrict__ scale,
                         const float* __restrict__ shift, const half8_t* __restrict__ wp,
                         const float* __restrict__ as, const float* __restrict__ ad,
                         __half* __restrict__ xw, float* __restrict__ al_s, float* __restrict__ al_d) {
    const int l = threadIdx.x;
    const int row0 = blockIdx.x * 16;
    const int c = l & 15, g = l >> 4;
    const float* xrow = x + (size_t)(row0 + c) * D1;

    f32x4_t acc[4];
#pragma unroll
    for (int nt = 0; nt < 4; nt++) acc[nt] = (f32x4_t){0.f, 0.f, 0.f, 0.f};

#pragma unroll
    for (int kk = 0; kk < 4; kk++) {
        const int koff = kk * 32 + g * 8;
        f32x4_t a0 = *(const f32x4_t*)(xrow + koff);
        f32x4_t a1 = *(const f32x4_t*)(xrow + koff + 4);
        f32x4_t sc0 = *(const f32x4_t*)(scale + koff);
        f32x4_t sc1 = *(const f32x4_t*)(scale + koff + 4);
        f32x4_t sh0 = *(const f32x4_t*)(shift + koff);
        f32x4_t sh1 = *(const f32x4_t*)(shift + koff + 4);
        half8_t af;
#pragma unroll
        for (int i = 0; i < 4; i++) {
            af[i]     = (_Float16)lrelu(a0[i] * sc0[i] + sh0[i], 0.01f);
            af[i + 4] = (_Float16)lrelu(a1[i] * sc1[i] + sh1[i], 0.01f);
        }
#pragma unroll
        for (int nt = 0; nt < 4; nt++) {
            half8_t bf = wp[(kk * 4 + nt) * 64 + l];
            acc[nt] = __builtin_amdgcn_mfma_f32_16x16x32_f16(af, bf, acc[nt], 0, 0, 0);
        }
    }

    float asv[4], adv[4];
#pragma unroll
    for (int nt = 0; nt < 4; nt++) { asv[nt] = as[nt * 16 + c]; adv[nt] = ad[nt * 16 + c]; }

#pragma unroll
    for (int r = 0; r < 4; r++) {
        const int row = row0 + g * 4 + r;
        __half* xwr = xw + (size_t)row * D2;
        float hs = 0.f, hd = 0.f;
#pragma unroll
        for (int nt = 0; nt < 4; nt++) {
            float v = acc[nt][r];
            xwr[nt * 16 + c] = __float2half(v);
            hs += v * asv[nt];
            hd += v * adv[nt];
        }
#pragma unroll
        for (int m = 1; m <= 8; m <<= 1) { hs += __shfl_xor(hs, m); hd += __shfl_xor(hd, m); }
        if (c == 0) { al_s[row] = hs; al_d[row] = hd; }
    }
}

// ---------------- fused GAT layer 2: one wave per destination, register-only ----------------
__global__ void k_gat2(const int* __restrict__ row_ptr, const u16* __restrict__ csr_src,
                       const float* __restrict__ als, const float* __restrict__ ald,
                       const __half2* __restrict__ xw, float* __restrict__ out) {
    const int d = blockIdx.x;
    const int beg = row_ptr[d];
    const int deg = row_ptr[d + 1] - beg;
    const int lane = threadIdx.x;
    const int sub = lane >> 5, l = lane & 31;

    const float add = ald[d];
    float ax = 0.f, ay = 0.f, den = 0.f;
    for (int base = 0; base < deg; base += 64) {
        int cnt = min(64, deg - base);
        int s = 0; float e = 0.f;
        if (lane < cnt) {
            s = csr_src[beg + base + lane];
            e = __expf(lrelu(als[s] + add, 0.2f));
        }
        int np = (cnt + 1) >> 1;
        for (int i = 0; i < np; i++) {
            int idx = 2 * i + sub;
            float al = __shfl(e, idx);
            int  si  = __shfl(s, idx);
            float2 v = __half22float2(xw[(size_t)si * 32 + l]);
            den += al; ax += al * v.x; ay += al * v.y;
        }
    }
    ax += __shfl_xor(ax, 32); ay += __shfl_xor(ay, 32); den += __shfl_xor(den, 32);
    if (lane < 32) {
        float inv = 1.f / (den + 1e-16f);
        *(float2*)(out + (size_t)d * D2 + 2 * l) = make_float2(ax * inv, ay * inv);
    }
}

extern "C" void kernel_launch(void* const* d_in, const int* in_sizes, int n_in,
                              void* d_out, int out_size, void* d_ws, size_t ws_size,
                              hipStream_t stream) {
    const float* x   = (const float*)d_in[0];
    const int*   ei  = (const int*)d_in[2];
    const float* W1  = (const float*)d_in[3];
    const float* as1 = (const float*)d_in[4];
    const float* ad1 = (const float*)d_in[5];
    const float* g1  = (const float*)d_in[7];
    const float* be1 = (const float*)d_in[8];
    const float* W2  = (const float*)d_in[9];
    const float* as2 = (const float*)d_in[10];
    const float* ad2 = (const float*)d_in[11];
    const float* g2  = (const float*)d_in[13];
    const float* be2 = (const float*)d_in[14];
    float* out = (float*)d_out;

    float* ws = (float*)d_ws;
    // layout (float offsets); footprint identical to R6 (proven < ws_size)
    __half* xw1  = (__half*)ws;          // 6.4M halves; dead after gat1
    __half* xw2  = (__half*)ws;          // 3.2M halves (layer 2)
    float* bp    = ws + 1600000;         // 2*NBP*128 floats (dead-xw1 area)
    float* al_s2 = ws + 3200000;         // 50k
    float* al_d2 = ws + 3250000;         // 50k
    float* al_s1 = ws + 6400000;         // 200k
    float* al_d1 = al_s1 + 200000;       // 200k
    float* agg1  = al_d1 + 200000;       // 6.4M
    int*   row_ptr = (int*)(agg1 + 6400000);  // 50,001 ints
    int*   cur     = row_ptr + 50001;         // 50,000 ints
    int*   part    = cur + 50000;             // 199 ints (pad for 16B-aligned st)
    float* st      = (float*)(part + 199);    // 384 floats
    u16*   csr_src = (u16*)(st + 768);        // 850,000 u16
    __half* Wp1    = (__half*)(csr_src + 850000);  // 16384 halves
    __half* Wp2    = Wp1 + 16384;                  // 8192 halves

    // ---- init + CSR build (XCD-sharded hist/fill) ----
    k_prepw<<<196, 256, 0, stream>>>(W1, W2, Wp1, Wp2, cur);
    k_hist_x<<<2048, 256, 0, stream>>>(ei, cur);
    k_blocksum<<<NB_SCAN, 256, 0, stream>>>(cur, part);
    k_scanpart<<<1, 256, 0, stream>>>(part);
    k_scanfinal<<<NB_SCAN, 256, 0, stream>>>(cur, part, row_ptr, cur);
    k_fill_x<<<2048, 256, 0, stream>>>(ei, cur, csr_src);

    // ---- layer 1 ----
    k_gemm1m<<<NN / 16, 64, 0, stream>>>(x, (const half8_t*)Wp1, as1, ad1, xw1, al_s1, al_d1);
    k_gat1<<<NN, 64, 0, stream>>>(row_ptr, csr_src, al_s1, al_d1, (const __half2*)xw1, agg1);
    k_bnstats<D1><<<NBP, D1, 0, stream>>>(agg1, bp);
    k_bnreduce<D1><<<D1, 256, 0, stream>>>(bp, g1, be1, st, st + 128);

    // ---- layer 2 (BN1 apply fused into gemm2's A-read) ----
    k_gemm2m<<<NN / 16, 64, 0, stream>>>(agg1, st, st + 128, (const half8_t*)Wp2, as2, ad2, xw2, al_s2, al_d2);
    k_gat2<<<NN, 64, 0, stream>>>(row_ptr, csr_src, al_s2, al_d2, (const __half2*)xw2, out);
    k_bnstats<D2><<<NBP, D2, 0, stream>>>(out, bp);
    k_bnreduce<D2><<<D2, 256, 0, stream>>>(bp, g2, be2, st + 256, st + 320);
    k_bnapply2<<<(NN * D2 / 4 + 255) / 256, 256, 0, stream>>>(out, st + 256, st + 320, out);
}

// Round 8
// 211.225 us; speedup vs baseline: 12.0055x; 1.0785x over previous
//
#include <hip/hip_runtime.h>
#include <hip/hip_fp16.h>

#define NN 50000        // nodes
#define NE 800000       // edges (without self loops)
#define ET 850000       // edges + self loops
#define GD 128          // input feature dim
#define D1 128          // HEADS*H1
#define NH 4            // heads layer 1
#define D2 64           // layer-2 dim
#define NB_SCAN 196     // ceil(NN/256)
#define NBP 1024        // bn partial blocks
#define NXCD 8
#define NPX 6250        // nodes per XCD shard
#define HB 1024         // hist blocks inside k_histgemm1

typedef unsigned short u16;
typedef _Float16 half8_t __attribute__((ext_vector_type(8)));
typedef float    f32x4_t __attribute__((ext_vector_type(4)));

__device__ __forceinline__ float lrelu(float x, float s) { return x > 0.f ? x : s * x; }

// ---------------- fused init: zero counters + permute/cvt weights ----------------
// Wp[( kk*NT + nt )*64 + l][i] = W[(kk*32 + (l>>4)*8 + i) * N + nt*16 + (l&15)]
__global__ void k_prepw(const float* __restrict__ W1, const float* __restrict__ W2,
                        __half* __restrict__ Wp1, __half* __restrict__ Wp2,
                        int* __restrict__ cur) {
    int idx = blockIdx.x * 256 + threadIdx.x;
    if (idx < NN) cur[idx] = 0;
    if (idx < 16384) {
        int i = idx & 7, l = (idx >> 3) & 63, nt = (idx >> 9) & 7, kk = idx >> 12;
        int k = kk * 32 + (l >> 4) * 8 + i, n = nt * 16 + (l & 15);
        Wp1[idx] = __float2half(W1[k * D1 + n]);
    } else if (idx < 24576) {
        int x2 = idx - 16384;
        int i = x2 & 7, l = (x2 >> 3) & 63, nt = (x2 >> 9) & 3, kk = x2 >> 11;
        int k = kk * 32 + (l >> 4) * 8 + i, n = nt * 16 + (l & 15);
        Wp2[x2] = __float2half(W2[k * D2 + n]);
    }
}

// ---------------- fused: XCD-sharded histogram (blocks [0,HB)) + MFMA GEMM1 ----------------
__global__ void k_histgemm1(const int* __restrict__ ei, int* __restrict__ cnt,
                            const float* __restrict__ x, const half8_t* __restrict__ wp,
                            const float* __restrict__ as, const float* __restrict__ ad,
                            __half* __restrict__ xw, float* __restrict__ al_s,
                            float* __restrict__ al_d) {
    if (blockIdx.x < HB) {
        const int xcd = blockIdx.x & (NXCD - 1);
        const int grp = blockIdx.x >> 3;
        const int ngrp = HB >> 3;
        const int lo = xcd * NPX, hi = lo + NPX;
        for (int e = grp * 256 + threadIdx.x; e < ET; e += ngrp * 256) {
            int d = (e < NE) ? ei[NE + e] : (e - NE);
            if (d >= lo && d < hi) atomicAdd(&cnt[d], 1);
        }
        return;
    }
    const int strip = (blockIdx.x - HB) * 4 + (threadIdx.x >> 6);
    if (strip >= NN / 16) return;
    const int l = threadIdx.x & 63;
    const int row0 = strip * 16;
    const int c = l & 15, g = l >> 4;
    const float* xrow = x + (size_t)(row0 + c) * GD;

    f32x4_t acc[8];
#pragma unroll
    for (int nt = 0; nt < 8; nt++) acc[nt] = (f32x4_t){0.f, 0.f, 0.f, 0.f};

#pragma unroll
    for (int kk = 0; kk < 4; kk++) {
        const int koff = kk * 32 + g * 8;
        f32x4_t a0 = *(const f32x4_t*)(xrow + koff);
        f32x4_t a1 = *(const f32x4_t*)(xrow + koff + 4);
        half8_t af;
#pragma unroll
        for (int i = 0; i < 4; i++) { af[i] = (_Float16)a0[i]; af[i + 4] = (_Float16)a1[i]; }
#pragma unroll
        for (int nt = 0; nt < 8; nt++) {
            half8_t bf = wp[(kk * 8 + nt) * 64 + l];
            acc[nt] = __builtin_amdgcn_mfma_f32_16x16x32_f16(af, bf, acc[nt], 0, 0, 0);
        }
    }

    float asv[8], adv[8];
#pragma unroll
    for (int nt = 0; nt < 8; nt++) { asv[nt] = as[nt * 16 + c]; adv[nt] = ad[nt * 16 + c]; }

#pragma unroll
    for (int r = 0; r < 4; r++) {
        const int row = row0 + g * 4 + r;
        __half* xwr = xw + (size_t)row * D1;
        float hs[4] = {0.f, 0.f, 0.f, 0.f}, hd[4] = {0.f, 0.f, 0.f, 0.f};
#pragma unroll
        for (int nt = 0; nt < 8; nt++) {
            float v = acc[nt][r];
            xwr[nt * 16 + c] = __float2half(v);
            hs[nt >> 1] += v * asv[nt];
            hd[nt >> 1] += v * adv[nt];
        }
#pragma unroll
        for (int m = 1; m <= 8; m <<= 1) {
#pragma unroll
            for (int h = 0; h < 4; h++) { hs[h] += __shfl_xor(hs[h], m); hd[h] += __shfl_xor(hd[h], m); }
        }
        if (c == 0) {
#pragma unroll
            for (int h = 0; h < 4; h++) { al_s[row * NH + h] = hs[h]; al_d[row * NH + h] = hd[h]; }
        }
    }
}

// ---------------- scan: per-block sums ----------------
__global__ void k_blocksum(const int* __restrict__ cnt, int* __restrict__ part) {
    __shared__ int r[256];
    int t = threadIdx.x, i = blockIdx.x * 256 + t;
    r[t] = (i < NN) ? cnt[i] : 0;
    __syncthreads();
    for (int s = 128; s >= 1; s >>= 1) {
        if (t < s) r[t] += r[t + s];
        __syncthreads();
    }
    if (t == 0) part[blockIdx.x] = r[0];
}

// merged scanpart+scanfinal: every block re-scans the 196 partials in LDS
__global__ void k_scanfix(const int* __restrict__ cnt, const int* __restrict__ part,
                          int* __restrict__ row_ptr, int* __restrict__ cur) {
    __shared__ int pp[256];
    __shared__ int r[256];
    int b = blockIdx.x, t = threadIdx.x, i = b * 256 + t;
    pp[t] = (t < NB_SCAN) ? part[t] : 0;
    int v = (i < NN) ? cnt[i] : 0;
    r[t] = v;
    __syncthreads();
    for (int off = 1; off < 256; off <<= 1) {
        int pv = (t >= off) ? pp[t - off] : 0;
        int rv = (t >= off) ? r[t - off] : 0;
        __syncthreads();
        pp[t] += pv; r[t] += rv;
        __syncthreads();
    }
    int pbase = b ? pp[b - 1] : 0;
    if (i < NN) {
        int rp = pbase + (t ? r[t - 1] : 0);
        row_ptr[i] = rp;
        cur[i] = rp;
    }
    if (i == NN - 1) row_ptr[NN] = pbase + r[t];
}

// ---------------- XCD-sharded CSR fill ----------------
__global__ void k_fill_x(const int* __restrict__ ei, int* __restrict__ cur,
                         u16* __restrict__ csr_src) {
    const int xcd = blockIdx.x & (NXCD - 1);
    const int grp = blockIdx.x >> 3;
    const int ngrp = gridDim.x >> 3;
    const int lo = xcd * NPX, hi = lo + NPX;
    for (int e = grp * 256 + threadIdx.x; e < ET; e += ngrp * 256) {
        int d = (e < NE) ? ei[NE + e] : (e - NE);
        if (d >= lo && d < hi) {
            int s = (e < NE) ? ei[e] : d;
            int pos = atomicAdd(&cur[d], 1);
            csr_src[pos] = (u16)s;
        }
    }
}

// ---------------- fused GAT layer 1: one wave per destination, fp16 out ----------------
// blockIdx swizzled so node d's block lands on the XCD that built its csr shard
__global__ void k_gat1(const int* __restrict__ row_ptr, const u16* __restrict__ csr_src,
                       const float* __restrict__ als, const float* __restrict__ ald,
                       const __half2* __restrict__ xw, __half2* __restrict__ out) {
    const int b = blockIdx.x;
    const int d = (b & (NXCD - 1)) * NPX + (b >> 3);
    const int beg = row_ptr[d];
    const int deg = row_ptr[d + 1] - beg;
    const int lane = threadIdx.x;  // 64

    __shared__ int   s_src[64];
    __shared__ float s_al[64 * NH];

    const float4 adv = *(const float4*)(ald + d * NH);
    const int h = lane >> 4;

    float ax = 0.f, ay = 0.f, den = 0.f;
    for (int base = 0; base < deg; base += 64) {
        int cnt = min(64, deg - base);
        if (lane < cnt) {
            int s = csr_src[beg + base + lane];
            s_src[lane] = s;
            const float4 a = *(const float4*)(als + s * NH);
            s_al[lane * NH + 0] = __expf(lrelu(a.x + adv.x, 0.2f));
            s_al[lane * NH + 1] = __expf(lrelu(a.y + adv.y, 0.2f));
            s_al[lane * NH + 2] = __expf(lrelu(a.z + adv.z, 0.2f));
            s_al[lane * NH + 3] = __expf(lrelu(a.w + adv.w, 0.2f));
        }
        __syncthreads();
#pragma unroll 4
        for (int i = 0; i < cnt; i++) {
            float al = s_al[i * NH + h];
            float2 v = __half22float2(xw[(size_t)s_src[i] * 64 + lane]);
            den += al; ax += al * v.x; ay += al * v.y;
        }
        __syncthreads();
    }
    float inv = 1.f / (den + 1e-16f);
    __half2 hv;
    hv.x = __float2half(ax * inv);
    hv.y = __float2half(ay * inv);
    out[(size_t)d * 64 + lane] = hv;
}

// ---------------- BN1 stats from fp16 agg (partials, no atomics) ----------------
__global__ void k_bnstats1h(const __half2* __restrict__ x, float* __restrict__ bp) {
    int t = threadIdx.x, bid = blockIdx.x;  // 64 threads
    float s0 = 0.f, q0 = 0.f, s1 = 0.f, q1 = 0.f;
    for (int r = bid; r < NN; r += NBP) {
        float2 f = __half22float2(x[(size_t)r * 64 + t]);
        s0 += f.x; q0 += f.x * f.x;
        s1 += f.y; q1 += f.y * f.y;
    }
    bp[bid * D1 + 2 * t] = s0;
    bp[bid * D1 + 2 * t + 1] = s1;
    bp[NBP * D1 + bid * D1 + 2 * t] = q0;
    bp[NBP * D1 + bid * D1 + 2 * t + 1] = q1;
}

template <int D>
__global__ void k_bnstats(const float* __restrict__ x, float* __restrict__ bp) {
    int j = threadIdx.x, bid = blockIdx.x;
    float s = 0.f, q = 0.f;
    for (int r = bid; r < NN; r += NBP) {
        float v = x[(size_t)r * D + j];
        s += v; q += v * v;
    }
    bp[bid * D + j] = s;
    bp[NBP * D + bid * D + j] = q;
}

template <int D>
__global__ void k_bnreduce(const float* __restrict__ bp, const float* __restrict__ g,
                           const float* __restrict__ b, float* __restrict__ scale,
                           float* __restrict__ shift) {
    __shared__ float rs[256], rq[256];
    int j = blockIdx.x, t = threadIdx.x;
    float s = 0.f, q = 0.f;
    for (int i = t; i < NBP; i += 256) {
        s += bp[i * D + j];
        q += bp[NBP * D + i * D + j];
    }
    rs[t] = s; rq[t] = q;
    __syncthreads();
    for (int st = 128; st >= 1; st >>= 1) {
        if (t < st) { rs[t] += rs[t + st]; rq[t] += rq[t + st]; }
        __syncthreads();
    }
    if (t == 0) {
        float mu = rs[0] / (float)NN;
        float var = rq[0] / (float)NN - mu * mu;
        float sc = rsqrtf(var + 1e-5f) * g[j];
        scale[j] = sc;
        shift[j] = b[j] - mu * sc;
    }
}

// final BN+lrelu for layer-2 output (float4)
__global__ void k_bnapply2(const float* __restrict__ x, const float* __restrict__ scale,
                           const float* __restrict__ shift, float* __restrict__ y) {
    int idx = blockIdx.x * blockDim.x + threadIdx.x;
    if (idx >= NN * D2 / 4) return;
    float4 v = ((const float4*)x)[idx];
    int c = (idx * 4) & (D2 - 1);
    v.x = lrelu(v.x * scale[c + 0] + shift[c + 0], 0.01f);
    v.y = lrelu(v.y * scale[c + 1] + shift[c + 1], 0.01f);
    v.z = lrelu(v.z * scale[c + 2] + shift[c + 2], 0.01f);
    v.w = lrelu(v.w * scale[c + 3] + shift[c + 3], 0.01f);
    ((float4*)y)[idx] = v;
}

// ---------------- GEMM2 via MFMA, fp16 A in, fused BN1-apply + lrelu ----------------
__global__ void k_gemm2m(const __half* __restrict__ x, const float* __restrict__ scale,
                         const float* __restrict__ shift, const half8_t* __restrict__ wp,
                         const float* __restrict__ as, const float* __restrict__ ad,
                         __half* __restrict__ xw, float* __restrict__ al_s, float* __restrict__ al_d) {
    const int l = threadIdx.x;
    const int row0 = blockIdx.x * 16;
    const int c = l & 15, g = l >> 4;
    const __half* xrow = x + (size_t)(row0 + c) * D1;

    f32x4_t acc[4];
#pragma unroll
    for (int nt = 0; nt < 4; nt++) acc[nt] = (f32x4_t){0.f, 0.f, 0.f, 0.f};

#pragma unroll
    for (int kk = 0; kk < 4; kk++) {
        const int koff = kk * 32 + g * 8;
        half8_t a8 = *(const half8_t*)(xrow + koff);
        f32x4_t sc0 = *(const f32x4_t*)(scale + koff);
        f32x4_t sc1 = *(const f32x4_t*)(scale + koff + 4);
        f32x4_t sh0 = *(const f32x4_t*)(shift + koff);
        f32x4_t sh1 = *(const f32x4_t*)(shift + koff + 4);
        half8_t af;
#pragma unroll
        for (int i = 0; i < 4; i++) {
            af[i]     = (_Float16)lrelu((float)a8[i] * sc0[i] + sh0[i], 0.01f);
            af[i + 4] = (_Float16)lrelu((float)a8[i + 4] * sc1[i] + sh1[i], 0.01f);
        }
#pragma unroll
        for (int nt = 0; nt < 4; nt++) {
            half8_t bf = wp[(kk * 4 + nt) * 64 + l];
            acc[nt] = __builtin_amdgcn_mfma_f32_16x16x32_f16(af, bf, acc[nt], 0, 0, 0);
        }
    }

    float asv[4], adv[4];
#pragma unroll
    for (int nt = 0; nt < 4; nt++) { asv[nt] = as[nt * 16 + c]; adv[nt] = ad[nt * 16 + c]; }

#pragma unroll
    for (int r = 0; r < 4; r++) {
        const int row = row0 + g * 4 + r;
        __half* xwr = xw + (size_t)row * D2;
        float hs = 0.f, hd = 0.f;
#pragma unroll
        for (int nt = 0; nt < 4; nt++) {
            float v = acc[nt][r];
            xwr[nt * 16 + c] = __float2half(v);
            hs += v * asv[nt];
            hd += v * adv[nt];
        }
#pragma unroll
        for (int m = 1; m <= 8; m <<= 1) { hs += __shfl_xor(hs, m); hd += __shfl_xor(hd, m); }
        if (c == 0) { al_s[row] = hs; al_d[row] = hd; }
    }
}

// ---------------- fused GAT layer 2: one wave per destination, register-only ----------------
__global__ void k_gat2(const int* __restrict__ row_ptr, const u16* __restrict__ csr_src,
                       const float* __restrict__ als, const float* __restrict__ ald,
                       const __half2* __restrict__ xw, float* __restrict__ out) {
    const int b = blockIdx.x;
    const int d = (b & (NXCD - 1)) * NPX + (b >> 3);
    const int beg = row_ptr[d];
    const int deg = row_ptr[d + 1] - beg;
    const int lane = threadIdx.x;
    const int sub = lane >> 5, l = lane & 31;

    const float add = ald[d];
    float ax = 0.f, ay = 0.f, den = 0.f;
    for (int base = 0; base < deg; base += 64) {
        int cnt = min(64, deg - base);
        int s = 0; float e = 0.f;
        if (lane < cnt) {
            s = csr_src[beg + base + lane];
            e = __expf(lrelu(als[s] + add, 0.2f));
        }
        int np = (cnt + 1) >> 1;
        for (int i = 0; i < np; i++) {
            int idx = 2 * i + sub;
            float al = __shfl(e, idx);
            int  si  = __shfl(s, idx);
            float2 v = __half22float2(xw[(size_t)si * 32 + l]);
            den += al; ax += al * v.x; ay += al * v.y;
        }
    }
    ax += __shfl_xor(ax, 32); ay += __shfl_xor(ay, 32); den += __shfl_xor(den, 32);
    if (lane < 32) {
        float inv = 1.f / (den + 1e-16f);
        *(float2*)(out + (size_t)d * D2 + 2 * l) = make_float2(ax * inv, ay * inv);
    }
}

extern "C" void kernel_launch(void* const* d_in, const int* in_sizes, int n_in,
                              void* d_out, int out_size, void* d_ws, size_t ws_size,
                              hipStream_t stream) {
    const float* x   = (const float*)d_in[0];
    const int*   ei  = (const int*)d_in[2];
    const float* W1  = (const float*)d_in[3];
    const float* as1 = (const float*)d_in[4];
    const float* ad1 = (const float*)d_in[5];
    const float* g1  = (const float*)d_in[7];
    const float* be1 = (const float*)d_in[8];
    const float* W2  = (const float*)d_in[9];
    const float* as2 = (const float*)d_in[10];
    const float* ad2 = (const float*)d_in[11];
    const float* g2  = (const float*)d_in[13];
    const float* be2 = (const float*)d_in[14];
    float* out = (float*)d_out;

    float* ws = (float*)d_ws;
    // layout (float offsets); footprint identical to R6/R7 (proven < ws_size)
    __half* xw1  = (__half*)ws;          // 6.4M halves; dead after gat1
    __half* xw2  = (__half*)ws;          // 3.2M halves (layer 2)
    float* bp    = ws + 1600000;         // 262144 floats of BN partials (dead-xw1 area)
    float* al_s2 = ws + 3200000;         // 50k
    float* al_d2 = ws + 3250000;         // 50k
    float* al_s1 = ws + 6400000;         // 200k
    float* al_d1 = al_s1 + 200000;       // 200k
    __half* agg1 = (__half*)(al_d1 + 200000);   // 6.4M halves (uses half of old region)
    float* aggE  = al_d1 + 200000 + 6400000;    // end of agg region (unchanged size)
    int*   row_ptr = (int*)aggE;              // 50,001 ints
    int*   cur     = row_ptr + 50001;         // 50,000 ints
    int*   part    = cur + 50000;             // 199 ints (pad for 16B-aligned st)
    float* st      = (float*)(part + 199);    // 384 floats
    u16*   csr_src = (u16*)(st + 768);        // 850,000 u16
    __half* Wp1    = (__half*)(csr_src + 850000);  // 16384 halves
    __half* Wp2    = Wp1 + 16384;                  // 8192 halves

    // ---- init + CSR build + GEMM1 (hist fused with gemm1) ----
    k_prepw<<<196, 256, 0, stream>>>(W1, W2, Wp1, Wp2, cur);
    k_histgemm1<<<HB + (NN / 16 + 3) / 4, 256, 0, stream>>>(ei, cur, x, (const half8_t*)Wp1,
                                                            as1, ad1, xw1, al_s1, al_d1);
    k_blocksum<<<NB_SCAN, 256, 0, stream>>>(cur, part);
    k_scanfix<<<NB_SCAN, 256, 0, stream>>>(cur, part, row_ptr, cur);
    k_fill_x<<<2048, 256, 0, stream>>>(ei, cur, csr_src);

    // ---- layer 1 ----
    k_gat1<<<NN, 64, 0, stream>>>(row_ptr, csr_src, al_s1, al_d1, (const __half2*)xw1,
                                  (__half2*)agg1);
    k_bnstats1h<<<NBP, 64, 0, stream>>>((const __half2*)agg1, bp);
    k_bnreduce<D1><<<D1, 256, 0, stream>>>(bp, g1, be1, st, st + 128);

    // ---- layer 2 (BN1 apply fused into gemm2's A-read) ----
    k_gemm2m<<<NN / 16, 64, 0, stream>>>(agg1, st, st + 128, (const half8_t*)Wp2, as2, ad2,
                                         xw2, al_s2, al_d2);
    k_gat2<<<NN, 64, 0, stream>>>(row_ptr, csr_src, al_s2, al_d2, (const __half2*)xw2, out);
    k_bnstats<D2><<<NBP, D2, 0, stream>>>(out, bp);
    k_bnreduce<D2><<<D2, 256, 0, stream>>>(bp, g2, be2, st + 256, st + 320);
    k_bnapply2<<<(NN * D2 / 4 + 255) / 256, 256, 0, stream>>>(out, st + 256, st + 320, out);
}

// Round 9
// 194.935 us; speedup vs baseline: 13.0088x; 1.0836x over previous
//
#include <hip/hip_runtime.h>
#include <hip/hip_fp16.h>

#define NN 50000        // nodes
#define NE 800000       // edges (without self loops)
#define ET 850000       // edges + self loops
#define GD 128          // input feature dim
#define D1 128          // HEADS*H1
#define NH 4            // heads layer 1
#define D2 64           // layer-2 dim
#define NB_SCAN 196     // ceil(NN/256)
#define NBP 1024        // bn partial blocks
#define NXCD 8
#define NPX 6250        // nodes per XCD shard
#define HB 4096         // hist blocks inside k_histgemm1

typedef unsigned short u16;
typedef _Float16 half8_t __attribute__((ext_vector_type(8)));
typedef float    f32x4_t __attribute__((ext_vector_type(4)));

__device__ __forceinline__ float lrelu(float x, float s) { return x > 0.f ? x : s * x; }

// ---------------- fused init: zero counters + permute/cvt weights ----------------
__global__ void k_prepw(const float* __restrict__ W1, const float* __restrict__ W2,
                        __half* __restrict__ Wp1, __half* __restrict__ Wp2,
                        int* __restrict__ cur) {
    int idx = blockIdx.x * 256 + threadIdx.x;
    if (idx < NN) cur[idx] = 0;
    if (idx < 16384) {
        int i = idx & 7, l = (idx >> 3) & 63, nt = (idx >> 9) & 7, kk = idx >> 12;
        int k = kk * 32 + (l >> 4) * 8 + i, n = nt * 16 + (l & 15);
        Wp1[idx] = __float2half(W1[k * D1 + n]);
    } else if (idx < 24576) {
        int x2 = idx - 16384;
        int i = x2 & 7, l = (x2 >> 3) & 63, nt = (x2 >> 9) & 3, kk = x2 >> 11;
        int k = kk * 32 + (l >> 4) * 8 + i, n = nt * 16 + (l & 15);
        Wp2[x2] = __float2half(W2[k * D2 + n]);
    }
}

// ---------------- fused: XCD-sharded histogram+pos (blocks [0,HB)) + MFMA GEMM1 ----------------
__global__ void k_histgemm1(const int* __restrict__ ei, int* __restrict__ cnt,
                            u16* __restrict__ pos16,
                            const float* __restrict__ x, const half8_t* __restrict__ wp,
                            const float* __restrict__ as, const float* __restrict__ ad,
                            __half* __restrict__ xw, float* __restrict__ al_s,
                            float* __restrict__ al_d) {
    if (blockIdx.x < HB) {
        const int xcd = blockIdx.x & (NXCD - 1);
        const int grp = blockIdx.x >> 3;
        const int ngrp = HB >> 3;
        const int lo = xcd * NPX, hi = lo + NPX;
        for (int e = grp * 256 + threadIdx.x; e < ET; e += ngrp * 256) {
            int d = (e < NE) ? ei[NE + e] : (e - NE);
            if (d >= lo && d < hi) {
                int pos = atomicAdd(&cnt[d], 1);
                pos16[e] = (u16)pos;
            }
        }
        return;
    }
    const int strip = (blockIdx.x - HB) * 4 + (threadIdx.x >> 6);
    if (strip >= NN / 16) return;
    const int l = threadIdx.x & 63;
    const int row0 = strip * 16;
    const int c = l & 15, g = l >> 4;
    const float* xrow = x + (size_t)(row0 + c) * GD;

    f32x4_t acc[8];
#pragma unroll
    for (int nt = 0; nt < 8; nt++) acc[nt] = (f32x4_t){0.f, 0.f, 0.f, 0.f};

#pragma unroll
    for (int kk = 0; kk < 4; kk++) {
        const int koff = kk * 32 + g * 8;
        f32x4_t a0 = *(const f32x4_t*)(xrow + koff);
        f32x4_t a1 = *(const f32x4_t*)(xrow + koff + 4);
        half8_t af;
#pragma unroll
        for (int i = 0; i < 4; i++) { af[i] = (_Float16)a0[i]; af[i + 4] = (_Float16)a1[i]; }
#pragma unroll
        for (int nt = 0; nt < 8; nt++) {
            half8_t bf = wp[(kk * 8 + nt) * 64 + l];
            acc[nt] = __builtin_amdgcn_mfma_f32_16x16x32_f16(af, bf, acc[nt], 0, 0, 0);
        }
    }

    float asv[8], adv[8];
#pragma unroll
    for (int nt = 0; nt < 8; nt++) { asv[nt] = as[nt * 16 + c]; adv[nt] = ad[nt * 16 + c]; }

#pragma unroll
    for (int r = 0; r < 4; r++) {
        const int row = row0 + g * 4 + r;
        __half* xwr = xw + (size_t)row * D1;
        float hs[4] = {0.f, 0.f, 0.f, 0.f}, hd[4] = {0.f, 0.f, 0.f, 0.f};
#pragma unroll
        for (int nt = 0; nt < 8; nt++) {
            float v = acc[nt][r];
            xwr[nt * 16 + c] = __float2half(v);
            hs[nt >> 1] += v * asv[nt];
            hd[nt >> 1] += v * adv[nt];
        }
#pragma unroll
        for (int m = 1; m <= 8; m <<= 1) {
#pragma unroll
            for (int h = 0; h < 4; h++) { hs[h] += __shfl_xor(hs[h], m); hd[h] += __shfl_xor(hd[h], m); }
        }
        if (c == 0) {
#pragma unroll
            for (int h = 0; h < 4; h++) { al_s[row * NH + h] = hs[h]; al_d[row * NH + h] = hd[h]; }
        }
    }
}

// ---------------- scan: per-block sums ----------------
__global__ void k_blocksum(const int* __restrict__ cnt, int* __restrict__ part) {
    __shared__ int r[256];
    int t = threadIdx.x, i = blockIdx.x * 256 + t;
    r[t] = (i < NN) ? cnt[i] : 0;
    __syncthreads();
    for (int s = 128; s >= 1; s >>= 1) {
        if (t < s) r[t] += r[t + s];
        __syncthreads();
    }
    if (t == 0) part[blockIdx.x] = r[0];
}

// merged scanpart+scanfinal: every block re-scans the 196 partials in LDS
__global__ void k_scanfix(const int* __restrict__ cnt, const int* __restrict__ part,
                          int* __restrict__ row_ptr) {
    __shared__ int pp[256];
    __shared__ int r[256];
    int b = blockIdx.x, t = threadIdx.x, i = b * 256 + t;
    pp[t] = (t < NB_SCAN) ? part[t] : 0;
    int v = (i < NN) ? cnt[i] : 0;
    r[t] = v;
    __syncthreads();
    for (int off = 1; off < 256; off <<= 1) {
        int pv = (t >= off) ? pp[t - off] : 0;
        int rv = (t >= off) ? r[t - off] : 0;
        __syncthreads();
        pp[t] += pv; r[t] += rv;
        __syncthreads();
    }
    int pbase = b ? pp[b - 1] : 0;
    if (i < NN) row_ptr[i] = pbase + (t ? r[t - 1] : 0);
    if (i == NN - 1) row_ptr[NN] = pbase + r[t];
}

// ---------------- XCD-sharded CSR fill (atomic-free via pos16) ----------------
__global__ void k_fill_x(const int* __restrict__ ei, const int* __restrict__ row_ptr,
                         const u16* __restrict__ pos16, u16* __restrict__ csr_src) {
    const int xcd = blockIdx.x & (NXCD - 1);
    const int grp = blockIdx.x >> 3;
    const int ngrp = gridDim.x >> 3;
    const int lo = xcd * NPX, hi = lo + NPX;
    for (int e = grp * 256 + threadIdx.x; e < ET; e += ngrp * 256) {
        int d = (e < NE) ? ei[NE + e] : (e - NE);
        if (d >= lo && d < hi) {
            int s = (e < NE) ? ei[e] : d;
            csr_src[row_ptr[d] + pos16[e]] = (u16)s;
        }
    }
}

// ---------------- fused GAT layer 1: one wave per destination, fp16 out ----------------
__global__ void k_gat1(const int* __restrict__ row_ptr, const u16* __restrict__ csr_src,
                       const float* __restrict__ als, const float* __restrict__ ald,
                       const __half2* __restrict__ xw, __half2* __restrict__ out) {
    const int b = blockIdx.x;
    const int d = (b & (NXCD - 1)) * NPX + (b >> 3);
    const int beg = row_ptr[d];
    const int deg = row_ptr[d + 1] - beg;
    const int lane = threadIdx.x;  // 64

    __shared__ int   s_src[64];
    __shared__ float s_al[64 * NH];

    const float4 adv = *(const float4*)(ald + d * NH);
    const int h = lane >> 4;

    float ax = 0.f, ay = 0.f, den = 0.f;
    for (int base = 0; base < deg; base += 64) {
        int cnt = min(64, deg - base);
        if (lane < cnt) {
            int s = csr_src[beg + base + lane];
            s_src[lane] = s;
            const float4 a = *(const float4*)(als + s * NH);
            s_al[lane * NH + 0] = __expf(lrelu(a.x + adv.x, 0.2f));
            s_al[lane * NH + 1] = __expf(lrelu(a.y + adv.y, 0.2f));
            s_al[lane * NH + 2] = __expf(lrelu(a.z + adv.z, 0.2f));
            s_al[lane * NH + 3] = __expf(lrelu(a.w + adv.w, 0.2f));
        }
        __syncthreads();
#pragma unroll 4
        for (int i = 0; i < cnt; i++) {
            float al = s_al[i * NH + h];
            float2 v = __half22float2(xw[(size_t)s_src[i] * 64 + lane]);
            den += al; ax += al * v.x; ay += al * v.y;
        }
        __syncthreads();
    }
    float inv = 1.f / (den + 1e-16f);
    __half2 hv;
    hv.x = __float2half(ax * inv);
    hv.y = __float2half(ay * inv);
    out[(size_t)d * 64 + lane] = hv;
}

// ---------------- BN1 stats from fp16 agg (partials, no atomics) ----------------
__global__ void k_bnstats1h(const __half2* __restrict__ x, float* __restrict__ bp) {
    int t = threadIdx.x, bid = blockIdx.x;  // 64 threads
    float s0 = 0.f, q0 = 0.f, s1 = 0.f, q1 = 0.f;
    for (int r = bid; r < NN; r += NBP) {
        float2 f = __half22float2(x[(size_t)r * 64 + t]);
        s0 += f.x; q0 += f.x * f.x;
        s1 += f.y; q1 += f.y * f.y;
    }
    bp[bid * D1 + 2 * t] = s0;
    bp[bid * D1 + 2 * t + 1] = s1;
    bp[NBP * D1 + bid * D1 + 2 * t] = q0;
    bp[NBP * D1 + bid * D1 + 2 * t + 1] = q1;
}

template <int D>
__global__ void k_bnstats(const float* __restrict__ x, float* __restrict__ bp) {
    int j = threadIdx.x, bid = blockIdx.x;
    float s = 0.f, q = 0.f;
    for (int r = bid; r < NN; r += NBP) {
        float v = x[(size_t)r * D + j];
        s += v; q += v * v;
    }
    bp[bid * D + j] = s;
    bp[NBP * D + bid * D + j] = q;
}

template <int D>
__global__ void k_bnreduce(const float* __restrict__ bp, const float* __restrict__ g,
                           const float* __restrict__ b, float* __restrict__ scale,
                           float* __restrict__ shift) {
    __shared__ float rs[256], rq[256];
    int j = blockIdx.x, t = threadIdx.x;
    float s = 0.f, q = 0.f;
    for (int i = t; i < NBP; i += 256) {
        s += bp[i * D + j];
        q += bp[NBP * D + i * D + j];
    }
    rs[t] = s; rq[t] = q;
    __syncthreads();
    for (int st = 128; st >= 1; st >>= 1) {
        if (t < st) { rs[t] += rs[t + st]; rq[t] += rq[t + st]; }
        __syncthreads();
    }
    if (t == 0) {
        float mu = rs[0] / (float)NN;
        float var = rq[0] / (float)NN - mu * mu;
        float sc = rsqrtf(var + 1e-5f) * g[j];
        scale[j] = sc;
        shift[j] = b[j] - mu * sc;
    }
}

// final BN+lrelu for layer-2 output (float4)
__global__ void k_bnapply2(const float* __restrict__ x, const float* __restrict__ scale,
                           const float* __restrict__ shift, float* __restrict__ y) {
    int idx = blockIdx.x * blockDim.x + threadIdx.x;
    if (idx >= NN * D2 / 4) return;
    float4 v = ((const float4*)x)[idx];
    int c = (idx * 4) & (D2 - 1);
    v.x = lrelu(v.x * scale[c + 0] + shift[c + 0], 0.01f);
    v.y = lrelu(v.y * scale[c + 1] + shift[c + 1], 0.01f);
    v.z = lrelu(v.z * scale[c + 2] + shift[c + 2], 0.01f);
    v.w = lrelu(v.w * scale[c + 3] + shift[c + 3], 0.01f);
    ((float4*)y)[idx] = v;
}

// ---------------- GEMM2 via MFMA, fp16 A in, fused BN1-apply + lrelu ----------------
__global__ void k_gemm2m(const __half* __restrict__ x, const float* __restrict__ scale,
                         const float* __restrict__ shift, const half8_t* __restrict__ wp,
                         const float* __restrict__ as, const float* __restrict__ ad,
                         __half* __restrict__ xw, float* __restrict__ al_s, float* __restrict__ al_d) {
    const int l = threadIdx.x;
    const int row0 = blockIdx.x * 16;
    const int c = l & 15, g = l >> 4;
    const __half* xrow = x + (size_t)(row0 + c) * D1;

    f32x4_t acc[4];
#pragma unroll
    for (int nt = 0; nt < 4; nt++) acc[nt] = (f32x4_t){0.f, 0.f, 0.f, 0.f};

#pragma unroll
    for (int kk = 0; kk < 4; kk++) {
        const int koff = kk * 32 + g * 8;
        half8_t a8 = *(const half8_t*)(xrow + koff);
        f32x4_t sc0 = *(const f32x4_t*)(scale + koff);
        f32x4_t sc1 = *(const f32x4_t*)(scale + koff + 4);
        f32x4_t sh0 = *(const f32x4_t*)(shift + koff);
        f32x4_t sh1 = *(const f32x4_t*)(shift + koff + 4);
        half8_t af;
#pragma unroll
        for (int i = 0; i < 4; i++) {
            af[i]     = (_Float16)lrelu((float)a8[i] * sc0[i] + sh0[i], 0.01f);
            af[i + 4] = (_Float16)lrelu((float)a8[i + 4] * sc1[i] + sh1[i], 0.01f);
        }
#pragma unroll
        for (int nt = 0; nt < 4; nt++) {
            half8_t bf = wp[(kk * 4 + nt) * 64 + l];
            acc[nt] = __builtin_amdgcn_mfma_f32_16x16x32_f16(af, bf, acc[nt], 0, 0, 0);
        }
    }

    float asv[4], adv[4];
#pragma unroll
    for (int nt = 0; nt < 4; nt++) { asv[nt] = as[nt * 16 + c]; adv[nt] = ad[nt * 16 + c]; }

#pragma unroll
    for (int r = 0; r < 4; r++) {
        const int row = row0 + g * 4 + r;
        __half* xwr = xw + (size_t)row * D2;
        float hs = 0.f, hd = 0.f;
#pragma unroll
        for (int nt = 0; nt < 4; nt++) {
            float v = acc[nt][r];
            xwr[nt * 16 + c] = __float2half(v);
            hs += v * asv[nt];
            hd += v * adv[nt];
        }
#pragma unroll
        for (int m = 1; m <= 8; m <<= 1) { hs += __shfl_xor(hs, m); hd += __shfl_xor(hd, m); }
        if (c == 0) { al_s[row] = hs; al_d[row] = hd; }
    }
}

// ---------------- fused GAT layer 2: one wave per destination, register-only ----------------
__global__ void k_gat2(const int* __restrict__ row_ptr, const u16* __restrict__ csr_src,
                       const float* __restrict__ als, const float* __restrict__ ald,
                       const __half2* __restrict__ xw, float* __restrict__ out) {
    const int b = blockIdx.x;
    const int d = (b & (NXCD - 1)) * NPX + (b >> 3);
    const int beg = row_ptr[d];
    const int deg = row_ptr[d + 1] - beg;
    const int lane = threadIdx.x;
    const int sub = lane >> 5, l = lane & 31;

    const float add = ald[d];
    float ax = 0.f, ay = 0.f, den = 0.f;
    for (int base = 0; base < deg; base += 64) {
        int cnt = min(64, deg - base);
        int s = 0; float e = 0.f;
        if (lane < cnt) {
            s = csr_src[beg + base + lane];
            e = __expf(lrelu(als[s] + add, 0.2f));
        }
        int np = (cnt + 1) >> 1;
        for (int i = 0; i < np; i++) {
            int idx = 2 * i + sub;
            float al = __shfl(e, idx);
            int  si  = __shfl(s, idx);
            float2 v = __half22float2(xw[(size_t)si * 32 + l]);
            den += al; ax += al * v.x; ay += al * v.y;
        }
    }
    ax += __shfl_xor(ax, 32); ay += __shfl_xor(ay, 32); den += __shfl_xor(den, 32);
    if (lane < 32) {
        float inv = 1.f / (den + 1e-16f);
        *(float2*)(out + (size_t)d * D2 + 2 * l) = make_float2(ax * inv, ay * inv);
    }
}

extern "C" void kernel_launch(void* const* d_in, const int* in_sizes, int n_in,
                              void* d_out, int out_size, void* d_ws, size_t ws_size,
                              hipStream_t stream) {
    const float* x   = (const float*)d_in[0];
    const int*   ei  = (const int*)d_in[2];
    const float* W1  = (const float*)d_in[3];
    const float* as1 = (const float*)d_in[4];
    const float* ad1 = (const float*)d_in[5];
    const float* g1  = (const float*)d_in[7];
    const float* be1 = (const float*)d_in[8];
    const float* W2  = (const float*)d_in[9];
    const float* as2 = (const float*)d_in[10];
    const float* ad2 = (const float*)d_in[11];
    const float* g2  = (const float*)d_in[13];
    const float* be2 = (const float*)d_in[14];
    float* out = (float*)d_out;

    float* ws = (float*)d_ws;
    // layout (float offsets); footprint identical to R6-R8 (proven < ws_size)
    __half* xw1  = (__half*)ws;          // 6.4M halves; dead after gat1
    __half* xw2  = (__half*)ws;          // 3.2M halves (layer 2)
    float* bp    = ws + 1600000;         // 262144 floats BN partials (live only after gat1)
    float* al_s2 = ws + 3200000;         // 50k
    float* al_d2 = ws + 3250000;         // 50k
    float* al_s1 = ws + 6400000;         // 200k
    float* al_d1 = al_s1 + 200000;       // 200k
    __half* agg1 = (__half*)(al_d1 + 200000);   // 6.4M halves (live only after fill)
    u16*   pos16 = (u16*)agg1;                  // 850k u16 — CSR-build phase only (pre-gat1)
    float* aggE  = al_d1 + 200000 + 6400000;
    int*   row_ptr = (int*)aggE;              // 50,001 ints
    int*   cur     = row_ptr + 50001;         // 50,000 ints (hist counters)
    int*   part    = cur + 50000;             // 199 ints (pad)
    float* st      = (float*)(part + 199);    // 384 floats
    u16*   csr_src = (u16*)(st + 768);        // 850,000 u16
    __half* Wp1    = (__half*)(csr_src + 850000);  // 16384 halves
    __half* Wp2    = Wp1 + 16384;                  // 8192 halves

    // ---- init + CSR build + GEMM1 (hist fused with gemm1; pos recorded) ----
    k_prepw<<<196, 256, 0, stream>>>(W1, W2, Wp1, Wp2, cur);
    k_histgemm1<<<HB + (NN / 16 + 3) / 4, 256, 0, stream>>>(ei, cur, pos16, x,
                                                            (const half8_t*)Wp1,
                                                            as1, ad1, xw1, al_s1, al_d1);
    k_blocksum<<<NB_SCAN, 256, 0, stream>>>(cur, part);
    k_scanfix<<<NB_SCAN, 256, 0, stream>>>(cur, part, row_ptr);
    k_fill_x<<<4096, 256, 0, stream>>>(ei, row_ptr, pos16, csr_src);

    // ---- layer 1 ----
    k_gat1<<<NN, 64, 0, stream>>>(row_ptr, csr_src, al_s1, al_d1, (const __half2*)xw1,
                                  (__half2*)agg1);
    k_bnstats1h<<<NBP, 64, 0, stream>>>((const __half2*)agg1, bp);
    k_bnreduce<D1><<<D1, 256, 0, stream>>>(bp, g1, be1, st, st + 128);

    // ---- layer 2 (BN1 apply fused into gemm2's A-read) ----
    k_gemm2m<<<NN / 16, 64, 0, stream>>>(agg1, st, st + 128, (const half8_t*)Wp2, as2, ad2,
                                         xw2, al_s2, al_d2);
    k_gat2<<<NN, 64, 0, stream>>>(row_ptr, csr_src, al_s2, al_d2, (const __half2*)xw2, out);
    k_bnstats<D2><<<NBP, D2, 0, stream>>>(out, bp);
    k_bnreduce<D2><<<D2, 256, 0, stream>>>(bp, g2, be2, st + 256, st + 320);
    k_bnapply2<<<(NN * D2 / 4 + 255) / 256, 256, 0, stream>>>(out, st + 256, st + 320, out);
}